// Round 1
// baseline (737.394 us; speedup 1.0000x reference)
//
#include <hip/hip_runtime.h>
#include <math.h>

#define BATCH 2
#define SEQ   2048
#define EMB   1024
#define NHEADS 16
#define HDIM  64
#define WHALF 256      // WINDOW_SIZE/2

// ---------------------------------------------------------------------------
// GEMM: C[M,N] = A[M,K] @ W[K,N] + bias[N]   (all fp32, row-major)
// 64x64 tile, BK=16, 256 threads, 4x4 microtile per thread.
// ---------------------------------------------------------------------------
#define BM 64
#define BN 64
#define BK 16

__global__ __launch_bounds__(256)
void gemm_bias_kernel(const float* __restrict__ A, const float* __restrict__ W,
                      const float* __restrict__ bias, float* __restrict__ C,
                      int M, int N, int K)
{
    __shared__ float As[BK][BM + 4];   // transposed A tile: As[k][m], +4 pad
    __shared__ float Bs[BK][BN + 4];

    const int tid = threadIdx.x;
    const int tx = tid & 15, ty = tid >> 4;
    const int row0 = blockIdx.y * BM;
    const int col0 = blockIdx.x * BN;

    float acc[4][4] = {};

    const int ar = tid >> 2;        // 0..63: row within A tile
    const int ak = (tid & 3) * 4;   // 0,4,8,12: k within A tile
    const int br = tid >> 4;        // 0..15: k within B tile
    const int bc = (tid & 15) * 4;  // col within B tile

    for (int k0 = 0; k0 < K; k0 += BK) {
        float4 a = *(const float4*)&A[(size_t)(row0 + ar) * K + k0 + ak];
        float4 b = *(const float4*)&W[(size_t)(k0 + br) * N + col0 + bc];
        As[ak + 0][ar] = a.x;
        As[ak + 1][ar] = a.y;
        As[ak + 2][ar] = a.z;
        As[ak + 3][ar] = a.w;
        *(float4*)&Bs[br][bc] = b;
        __syncthreads();
#pragma unroll
        for (int kk = 0; kk < BK; ++kk) {
            float4 av = *(const float4*)&As[kk][ty * 4];
            float4 bv = *(const float4*)&Bs[kk][tx * 4];
            float aa[4] = {av.x, av.y, av.z, av.w};
            float bb[4] = {bv.x, bv.y, bv.z, bv.w};
#pragma unroll
            for (int i = 0; i < 4; ++i)
#pragma unroll
                for (int j = 0; j < 4; ++j)
                    acc[i][j] = fmaf(aa[i], bb[j], acc[i][j]);
        }
        __syncthreads();
    }

    const float4 bvec = *(const float4*)&bias[col0 + tx * 4];
    const float bb[4] = {bvec.x, bvec.y, bvec.z, bvec.w};
#pragma unroll
    for (int i = 0; i < 4; ++i) {
        float4 o;
        o.x = acc[i][0] + bb[0];
        o.y = acc[i][1] + bb[1];
        o.z = acc[i][2] + bb[2];
        o.w = acc[i][3] + bb[3];
        *(float4*)&C[(size_t)(row0 + ty * 4 + i) * N + col0 + tx * 4] = o;
    }
}

// ---------------------------------------------------------------------------
// Sliding-window flash attention.
// Block: 256 threads, one (batch, head, 32-query tile).
// Iterates 64-key chunks over [q0-256, q0+31+256], online softmax.
// Q,K,V layout: [B, S, E] with head slice at column h*HDIM.
// Output written back over the Q buffer (same rows/slice this block read).
// ---------------------------------------------------------------------------
#define QT 32
#define KT 64

__global__ __launch_bounds__(256)
void attn_kernel(const float* __restrict__ Qm, const float* __restrict__ Km,
                 const float* __restrict__ Vm, float* __restrict__ Om)
{
    __shared__ float Qs[QT][HDIM + 4];
    __shared__ float KVs[KT][HDIM + 4];   // K chunk, then reused for V chunk
    __shared__ float Ps[QT][KT + 1];      // probs, +1 pad (kills 32-way conflict)
    __shared__ float red[8][QT];
    __shared__ float m_s[QT], l_s[QT], alpha_s[QT];

    const int tid = threadIdx.x;
    const int b  = blockIdx.y / NHEADS;
    const int h  = blockIdx.y % NHEADS;
    const int q0 = blockIdx.x * QT;

    const int r  = tid & 31;     // query row within tile
    const int cg = tid >> 5;     // 0..7 column/dim group
    const int d0 = cg * 8;

    // ---- load Q tile ----
    {
        const int qr = tid >> 3;         // 0..31
        const int qd = (tid & 7) * 8;    // 0..56
        const float* src = Qm + (size_t)(b * SEQ + q0 + qr) * EMB + h * HDIM + qd;
        *(float4*)&Qs[qr][qd]     = *(const float4*)(src);
        *(float4*)&Qs[qr][qd + 4] = *(const float4*)(src + 4);
    }
    if (tid < QT) { m_s[tid] = -1e30f; l_s[tid] = 0.0f; }
    __syncthreads();

    // q row of this thread into registers
    float qreg[HDIM];
#pragma unroll
    for (int d4 = 0; d4 < HDIM; d4 += 4) {
        float4 t = *(const float4*)&Qs[r][d4];
        qreg[d4] = t.x; qreg[d4 + 1] = t.y; qreg[d4 + 2] = t.z; qreg[d4 + 3] = t.w;
    }

    float o[8] = {};
    const int iq = q0 + r;

    int lo = q0 - WHALF; if (lo < 0) lo = 0;
    const int cs0 = lo & ~(KT - 1);
    int hi = q0 + QT + WHALF; if (hi > SEQ) hi = SEQ;
    const int nch = (hi - cs0 + KT - 1) / KT;

    const int kr0 = tid >> 4;        // 0..15
    const int kc  = (tid & 15) * 4;  // 0..60

    for (int ch = 0; ch < nch; ++ch) {
        const int cs = cs0 + ch * KT;

        // ---- load K chunk ----
#pragma unroll
        for (int r4 = 0; r4 < 4; ++r4) {
            const int row = kr0 + r4 * 16;
            const int j = cs + row;
            float4 v = make_float4(0.f, 0.f, 0.f, 0.f);
            if (j < SEQ)
                v = *(const float4*)&Km[(size_t)(b * SEQ + j) * EMB + h * HDIM + kc];
            *(float4*)&KVs[row][kc] = v;
        }
        __syncthreads();

        // ---- scores for (r, cols cg*8..cg*8+7) ----
        float s[8];
#pragma unroll
        for (int cc = 0; cc < 8; ++cc) {
            const int c = d0 + cc;
            float acc = 0.0f;
#pragma unroll
            for (int d4 = 0; d4 < HDIM; d4 += 4) {
                float4 kv = *(const float4*)&KVs[c][d4];
                acc = fmaf(qreg[d4],     kv.x, acc);
                acc = fmaf(qreg[d4 + 1], kv.y, acc);
                acc = fmaf(qreg[d4 + 2], kv.z, acc);
                acc = fmaf(qreg[d4 + 3], kv.w, acc);
            }
            const int j = cs + c;
            const bool valid = (j < SEQ) && (j >= iq - WHALF) && (j <= iq + WHALF);
            s[cc] = valid ? acc * 0.125f : -1e30f;
        }
        float lm = s[0];
#pragma unroll
        for (int cc = 1; cc < 8; ++cc) lm = fmaxf(lm, s[cc]);
        red[cg][r] = lm;
        __syncthreads();

        if (tid < QT) {
            float m = m_s[tid];
            float mc = red[0][tid];
#pragma unroll
            for (int g = 1; g < 8; ++g) mc = fmaxf(mc, red[g][tid]);
            const float mn = fmaxf(m, mc);
            alpha_s[tid] = __expf(m - mn);
            m_s[tid] = mn;
        }
        __syncthreads();

        const float mn = m_s[r];
        float ls = 0.0f;
#pragma unroll
        for (int cc = 0; cc < 8; ++cc) {
            const float p = __expf(s[cc] - mn);
            Ps[r][d0 + cc] = p;
            ls += p;
        }
        red[cg][r] = ls;
        __syncthreads();

        if (tid < QT) {
            float sum = red[0][tid];
#pragma unroll
            for (int g = 1; g < 8; ++g) sum += red[g][tid];
            l_s[tid] = l_s[tid] * alpha_s[tid] + sum;
        }

        // ---- load V chunk (overwrites K chunk; scores already consumed) ----
#pragma unroll
        for (int r4 = 0; r4 < 4; ++r4) {
            const int row = kr0 + r4 * 16;
            const int j = cs + row;
            float4 v = make_float4(0.f, 0.f, 0.f, 0.f);
            if (j < SEQ)
                v = *(const float4*)&Vm[(size_t)(b * SEQ + j) * EMB + h * HDIM + kc];
            *(float4*)&KVs[row][kc] = v;
        }
        // rescale running O by alpha (alpha_s stable until next chunk)
        {
            const float al = alpha_s[r];
#pragma unroll
            for (int dd = 0; dd < 8; ++dd) o[dd] *= al;
        }
        __syncthreads();

        // ---- accumulate P @ V:  o[dd] += P[r][j] * V[j][d0+dd] ----
        for (int j = 0; j < KT; ++j) {
            const float p = Ps[r][j];
            float4 v0 = *(const float4*)&KVs[j][d0];
            float4 v1 = *(const float4*)&KVs[j][d0 + 4];
            o[0] = fmaf(p, v0.x, o[0]);
            o[1] = fmaf(p, v0.y, o[1]);
            o[2] = fmaf(p, v0.z, o[2]);
            o[3] = fmaf(p, v0.w, o[3]);
            o[4] = fmaf(p, v1.x, o[4]);
            o[5] = fmaf(p, v1.y, o[5]);
            o[6] = fmaf(p, v1.z, o[6]);
            o[7] = fmaf(p, v1.w, o[7]);
        }
        __syncthreads();   // protect KVs/Ps/red before next chunk
    }

    const float inv = 1.0f / l_s[r];
    float4 o0, o1;
    o0.x = o[0] * inv; o0.y = o[1] * inv; o0.z = o[2] * inv; o0.w = o[3] * inv;
    o1.x = o[4] * inv; o1.y = o[5] * inv; o1.z = o[6] * inv; o1.w = o[7] * inv;
    float* dst = Om + (size_t)(b * SEQ + q0 + r) * EMB + h * HDIM + d0;
    *(float4*)dst       = o0;
    *(float4*)(dst + 4) = o1;
}

// ---------------------------------------------------------------------------
extern "C" void kernel_launch(void* const* d_in, const int* in_sizes, int n_in,
                              void* d_out, int out_size, void* d_ws, size_t ws_size,
                              hipStream_t stream)
{
    const float* x  = (const float*)d_in[0];
    const float* Wq = (const float*)d_in[1];
    const float* bq = (const float*)d_in[2];
    const float* Wk = (const float*)d_in[3];
    const float* bk = (const float*)d_in[4];
    const float* Wv = (const float*)d_in[5];
    const float* bv = (const float*)d_in[6];
    const float* Wo = (const float*)d_in[7];
    const float* bo = (const float*)d_in[8];
    float* out = (float*)d_out;

    const int M = BATCH * SEQ;                 // 4096
    float* Qb = (float*)d_ws;                  // 16.8 MB
    float* Kb = Qb + (size_t)M * EMB;          // 16.8 MB
    float* Vb = out;                           // V lives in d_out until final GEMM

    dim3 blk(256);
    dim3 ggrid(EMB / BN, M / BM);              // (16, 64)

    hipLaunchKernelGGL(gemm_bias_kernel, ggrid, blk, 0, stream, x, Wq, bq, Qb, M, EMB, EMB);
    hipLaunchKernelGGL(gemm_bias_kernel, ggrid, blk, 0, stream, x, Wk, bk, Kb, M, EMB, EMB);
    hipLaunchKernelGGL(gemm_bias_kernel, ggrid, blk, 0, stream, x, Wv, bv, Vb, M, EMB, EMB);

    dim3 agrid(SEQ / QT, BATCH * NHEADS);      // (64, 32)
    hipLaunchKernelGGL(attn_kernel, agrid, blk, 0, stream, Qb, Kb, Vb, Qb);

    // attn (in Qb) @ Wo + bo -> out (overwrites V, which is fully consumed)
    hipLaunchKernelGGL(gemm_bias_kernel, ggrid, blk, 0, stream, Qb, Wo, bo, out, M, EMB, EMB);
}

// Round 2
// 452.393 us; speedup vs baseline: 1.6300x; 1.6300x over previous
//
#include <hip/hip_runtime.h>
#include <math.h>
#include <stdint.h>

#define BATCH 2
#define SEQ   2048
#define EMB   1024
#define NHEADS 16
#define HDIM  64
#define WHALF 256      // WINDOW_SIZE/2

typedef __attribute__((ext_vector_type(8))) short short8;
typedef __attribute__((ext_vector_type(4))) float f32x4;

__device__ inline unsigned short f2bf_rn(float x) {
    uint32_t u = __float_as_uint(x);
    u += 0x7FFFu + ((u >> 16) & 1u);
    return (unsigned short)(u >> 16);
}
__device__ inline float bf2f(unsigned short b) {
    return __uint_as_float(((uint32_t)b) << 16);
}

// ---------------------------------------------------------------------------
// split fp32 -> bf16 hi/lo planes (elementwise, 4 per thread)
// ---------------------------------------------------------------------------
__global__ __launch_bounds__(256)
void split_bf16_kernel(const float* __restrict__ in, unsigned short* __restrict__ hi,
                       unsigned short* __restrict__ lo, int n)
{
    const int i = (blockIdx.x * 256 + threadIdx.x) * 4;
    if (i >= n) return;
    float4 v = *(const float4*)&in[i];
    ushort4 h, l;
    h.x = f2bf_rn(v.x); l.x = f2bf_rn(v.x - bf2f(h.x));
    h.y = f2bf_rn(v.y); l.y = f2bf_rn(v.y - bf2f(h.y));
    h.z = f2bf_rn(v.z); l.z = f2bf_rn(v.z - bf2f(h.z));
    h.w = f2bf_rn(v.w); l.w = f2bf_rn(v.w - bf2f(h.w));
    *(ushort4*)&hi[i] = h;
    *(ushort4*)&lo[i] = l;
}

// ---------------------------------------------------------------------------
// transpose + split the four 1024x1024 weights into one cat [4096][1024]
// bf16 hi/lo buffer: rows 0-1023 = Wq^T, 1024-2047 = Wk^T, 2048-3071 = Wv^T,
// 3072-4095 = Wo^T.
// ---------------------------------------------------------------------------
__global__ __launch_bounds__(256)
void wsplit_t_kernel(const float* __restrict__ W0, const float* __restrict__ W1,
                     const float* __restrict__ W2, const float* __restrict__ W3,
                     unsigned short* __restrict__ hi, unsigned short* __restrict__ lo)
{
    __shared__ float t[32][33];
    const float* W = (blockIdx.z == 0) ? W0 : (blockIdx.z == 1) ? W1
                   : (blockIdx.z == 2) ? W2 : W3;
    const int n0 = blockIdx.x * 32;   // col in W (output row)
    const int k0 = blockIdx.y * 32;   // row in W (output col)
    const int tx = threadIdx.x & 31, ty = threadIdx.x >> 5;   // ty 0..7
#pragma unroll
    for (int i = 0; i < 4; ++i)
        t[ty + i * 8][tx] = W[(size_t)(k0 + ty + i * 8) * EMB + n0 + tx];
    __syncthreads();
#pragma unroll
    for (int i = 0; i < 4; ++i) {
        float v = t[tx][ty + i * 8];
        unsigned short h = f2bf_rn(v);
        unsigned short l = f2bf_rn(v - bf2f(h));
        size_t o = (size_t)(blockIdx.z * EMB + n0 + ty + i * 8) * EMB + k0 + tx;
        hi[o] = h; lo[o] = l;
    }
}

__global__ __launch_bounds__(256)
void bias_cat_kernel(const float* __restrict__ bq, const float* __restrict__ bk,
                     const float* __restrict__ bv, float* __restrict__ out)
{
    const int i = blockIdx.x * 256 + threadIdx.x;
    if (i < 1024)      out[i] = bq[i];
    else if (i < 2048) out[i] = bk[i - 1024];
    else if (i < 3072) out[i] = bv[i - 2048];
}

// ---------------------------------------------------------------------------
// bf16x3 MFMA GEMM: C = (Ah+Al) @ (Bh+Bl)^T + bias  (drop Al*Bl term)
// A: [M][K] bf16 hi/lo.  B: [N][K] bf16 hi/lo (pre-transposed).
// 128x128 tile, BK=32, 256 threads = 4 waves in 2x2, 4x4 16x16x32 frags/wave.
// Output column split: cols < nsplit -> C0 (ldc0), else -> C1 (ldc1).
// ---------------------------------------------------------------------------
#define GLDS(gp, lp) __builtin_amdgcn_global_load_lds(                       \
    (const __attribute__((address_space(1))) void*)(gp),                     \
    (__attribute__((address_space(3))) void*)(lp), 16, 0, 0)

__global__ __launch_bounds__(256)
void gemm_mfma3_kernel(const unsigned short* __restrict__ Ah,
                       const unsigned short* __restrict__ Al,
                       const unsigned short* __restrict__ Bh,
                       const unsigned short* __restrict__ Bl,
                       const float* __restrict__ bias,
                       float* __restrict__ C0, int ldc0,
                       float* __restrict__ C1, int ldc1, int nsplit,
                       int K)
{
    __shared__ unsigned short sAh[128 * 32], sAl[128 * 32];
    __shared__ unsigned short sBh[128 * 32], sBl[128 * 32];

    const int tid = threadIdx.x;
    const int l = tid & 63;
    const int w = tid >> 6;
    const int wm = w >> 1, wn = w & 1;
    const int row0 = blockIdx.y * 128;
    const int col0 = blockIdx.x * 128;

    f32x4 acc[4][4] = {};

    // staging: idx = inst*256 + tid ; row = idx>>2 ; k-seg = (idx&3)*8
    const int sr = tid >> 2;
    const int sk = (tid & 3) * 8;
    const unsigned short* pAh = Ah + (size_t)(row0 + sr) * K + sk;
    const unsigned short* pAl = Al + (size_t)(row0 + sr) * K + sk;
    const unsigned short* pBh = Bh + (size_t)(col0 + sr) * K + sk;
    const unsigned short* pBl = Bl + (size_t)(col0 + sr) * K + sk;
    const size_t rstep = (size_t)64 * K;

    const int kq = (l >> 4) * 8;
    const int lr = l & 15;

    for (int k0 = 0; k0 < K; k0 += 32) {
        GLDS(pAh + k0,         &sAh[tid * 8]);
        GLDS(pAh + rstep + k0, &sAh[2048 + tid * 8]);
        GLDS(pAl + k0,         &sAl[tid * 8]);
        GLDS(pAl + rstep + k0, &sAl[2048 + tid * 8]);
        GLDS(pBh + k0,         &sBh[tid * 8]);
        GLDS(pBh + rstep + k0, &sBh[2048 + tid * 8]);
        GLDS(pBl + k0,         &sBl[tid * 8]);
        GLDS(pBl + rstep + k0, &sBl[2048 + tid * 8]);
        __syncthreads();

        short8 ah[4], al[4], bh[4], bl[4];
#pragma unroll
        for (int f = 0; f < 4; ++f) {
            ah[f] = *(const short8*)&sAh[(wm * 64 + f * 16 + lr) * 32 + kq];
            al[f] = *(const short8*)&sAl[(wm * 64 + f * 16 + lr) * 32 + kq];
            bh[f] = *(const short8*)&sBh[(wn * 64 + f * 16 + lr) * 32 + kq];
            bl[f] = *(const short8*)&sBl[(wn * 64 + f * 16 + lr) * 32 + kq];
        }
#pragma unroll
        for (int mf = 0; mf < 4; ++mf)
#pragma unroll
            for (int nf = 0; nf < 4; ++nf) {
                acc[mf][nf] = __builtin_amdgcn_mfma_f32_16x16x32_bf16(ah[mf], bh[nf], acc[mf][nf], 0, 0, 0);
                acc[mf][nf] = __builtin_amdgcn_mfma_f32_16x16x32_bf16(ah[mf], bl[nf], acc[mf][nf], 0, 0, 0);
                acc[mf][nf] = __builtin_amdgcn_mfma_f32_16x16x32_bf16(al[mf], bh[nf], acc[mf][nf], 0, 0, 0);
            }
        __syncthreads();
    }

    // epilogue: C/D layout col=lane&15, row=(lane>>4)*4+reg
    float* C; int ldc, cb;
    if (col0 < nsplit) { C = C0; ldc = ldc0; cb = col0; }
    else               { C = C1; ldc = ldc1; cb = col0 - nsplit; }
    const int lq = l >> 4;
#pragma unroll
    for (int nf = 0; nf < 4; ++nf) {
        const int c = wn * 64 + nf * 16 + lr;
        const float bv = bias[col0 + c];
        const int cc = cb + c;
#pragma unroll
        for (int mf = 0; mf < 4; ++mf) {
            const int r = row0 + wm * 64 + mf * 16 + lq * 4;
#pragma unroll
            for (int i = 0; i < 4; ++i)
                C[(size_t)(r + i) * ldc + cc] = acc[mf][nf][i] + bv;
        }
    }
}

// ---------------------------------------------------------------------------
// fp32 fallback GEMM (used only if ws_size is too small for the MFMA path)
// ---------------------------------------------------------------------------
#define BM 64
#define BN 64
#define BK 16

__global__ __launch_bounds__(256)
void gemm_bias_kernel(const float* __restrict__ A, const float* __restrict__ W,
                      const float* __restrict__ bias, float* __restrict__ C,
                      int M, int N, int K)
{
    __shared__ float As[BK][BM + 4];
    __shared__ float Bs[BK][BN + 4];

    const int tid = threadIdx.x;
    const int tx = tid & 15, ty = tid >> 4;
    const int row0 = blockIdx.y * BM;
    const int col0 = blockIdx.x * BN;

    float acc[4][4] = {};

    const int ar = tid >> 2;
    const int ak = (tid & 3) * 4;
    const int br = tid >> 4;
    const int bc = (tid & 15) * 4;

    for (int k0 = 0; k0 < K; k0 += BK) {
        float4 a = *(const float4*)&A[(size_t)(row0 + ar) * K + k0 + ak];
        float4 b = *(const float4*)&W[(size_t)(k0 + br) * N + col0 + bc];
        As[ak + 0][ar] = a.x;
        As[ak + 1][ar] = a.y;
        As[ak + 2][ar] = a.z;
        As[ak + 3][ar] = a.w;
        *(float4*)&Bs[br][bc] = b;
        __syncthreads();
#pragma unroll
        for (int kk = 0; kk < BK; ++kk) {
            float4 av = *(const float4*)&As[kk][ty * 4];
            float4 bv = *(const float4*)&Bs[kk][tx * 4];
            float aa[4] = {av.x, av.y, av.z, av.w};
            float bb[4] = {bv.x, bv.y, bv.z, bv.w};
#pragma unroll
            for (int i = 0; i < 4; ++i)
#pragma unroll
                for (int j = 0; j < 4; ++j)
                    acc[i][j] = fmaf(aa[i], bb[j], acc[i][j]);
        }
        __syncthreads();
    }

    const float4 bvec = *(const float4*)&bias[col0 + tx * 4];
    const float bb[4] = {bvec.x, bvec.y, bvec.z, bvec.w};
#pragma unroll
    for (int i = 0; i < 4; ++i) {
        float4 o;
        o.x = acc[i][0] + bb[0];
        o.y = acc[i][1] + bb[1];
        o.z = acc[i][2] + bb[2];
        o.w = acc[i][3] + bb[3];
        *(float4*)&C[(size_t)(row0 + ty * 4 + i) * N + col0 + tx * 4] = o;
    }
}

// ---------------------------------------------------------------------------
// Sliding-window flash attention (fp32), parametrized row strides.
// Block: 256 threads, one (batch, head, 32-query tile).
// ---------------------------------------------------------------------------
#define QT 32
#define KT 64

__global__ __launch_bounds__(256)
void attn_kernel(const float* __restrict__ Qm, int ldq,
                 const float* __restrict__ Km, int ldk,
                 const float* __restrict__ Vm, int ldv,
                 float* __restrict__ Om, int ldo)
{
    __shared__ float Qs[QT][HDIM + 4];
    __shared__ float KVs[KT][HDIM + 4];
    __shared__ float Ps[QT][KT + 1];
    __shared__ float red[8][QT];
    __shared__ float m_s[QT], l_s[QT], alpha_s[QT];

    const int tid = threadIdx.x;
    const int b  = blockIdx.y / NHEADS;
    const int h  = blockIdx.y % NHEADS;
    const int q0 = blockIdx.x * QT;

    const int r  = tid & 31;
    const int cg = tid >> 5;
    const int d0 = cg * 8;

    {
        const int qr = tid >> 3;
        const int qd = (tid & 7) * 8;
        const float* src = Qm + (size_t)(b * SEQ + q0 + qr) * ldq + h * HDIM + qd;
        *(float4*)&Qs[qr][qd]     = *(const float4*)(src);
        *(float4*)&Qs[qr][qd + 4] = *(const float4*)(src + 4);
    }
    if (tid < QT) { m_s[tid] = -1e30f; l_s[tid] = 0.0f; }
    __syncthreads();

    float qreg[HDIM];
#pragma unroll
    for (int d4 = 0; d4 < HDIM; d4 += 4) {
        float4 t = *(const float4*)&Qs[r][d4];
        qreg[d4] = t.x; qreg[d4 + 1] = t.y; qreg[d4 + 2] = t.z; qreg[d4 + 3] = t.w;
    }

    float o[8] = {};
    const int iq = q0 + r;

    int lo = q0 - WHALF; if (lo < 0) lo = 0;
    const int cs0 = lo & ~(KT - 1);
    int hi = q0 + QT + WHALF; if (hi > SEQ) hi = SEQ;
    const int nch = (hi - cs0 + KT - 1) / KT;

    const int kr0 = tid >> 4;
    const int kc  = (tid & 15) * 4;

    for (int ch = 0; ch < nch; ++ch) {
        const int cs = cs0 + ch * KT;

#pragma unroll
        for (int r4 = 0; r4 < 4; ++r4) {
            const int row = kr0 + r4 * 16;
            const int j = cs + row;
            float4 v = make_float4(0.f, 0.f, 0.f, 0.f);
            if (j < SEQ)
                v = *(const float4*)&Km[(size_t)(b * SEQ + j) * ldk + h * HDIM + kc];
            *(float4*)&KVs[row][kc] = v;
        }
        __syncthreads();

        float s[8];
#pragma unroll
        for (int cc = 0; cc < 8; ++cc) {
            const int c = d0 + cc;
            float acc = 0.0f;
#pragma unroll
            for (int d4 = 0; d4 < HDIM; d4 += 4) {
                float4 kv = *(const float4*)&KVs[c][d4];
                acc = fmaf(qreg[d4],     kv.x, acc);
                acc = fmaf(qreg[d4 + 1], kv.y, acc);
                acc = fmaf(qreg[d4 + 2], kv.z, acc);
                acc = fmaf(qreg[d4 + 3], kv.w, acc);
            }
            const int j = cs + c;
            const bool valid = (j < SEQ) && (j >= iq - WHALF) && (j <= iq + WHALF);
            s[cc] = valid ? acc * 0.125f : -1e30f;
        }
        float lm = s[0];
#pragma unroll
        for (int cc = 1; cc < 8; ++cc) lm = fmaxf(lm, s[cc]);
        red[cg][r] = lm;
        __syncthreads();

        if (tid < QT) {
            float m = m_s[tid];
            float mc = red[0][tid];
#pragma unroll
            for (int g = 1; g < 8; ++g) mc = fmaxf(mc, red[g][tid]);
            const float mn = fmaxf(m, mc);
            alpha_s[tid] = __expf(m - mn);
            m_s[tid] = mn;
        }
        __syncthreads();

        const float mn = m_s[r];
        float ls = 0.0f;
#pragma unroll
        for (int cc = 0; cc < 8; ++cc) {
            const float p = __expf(s[cc] - mn);
            Ps[r][d0 + cc] = p;
            ls += p;
        }
        red[cg][r] = ls;
        __syncthreads();

        if (tid < QT) {
            float sum = red[0][tid];
#pragma unroll
            for (int g = 1; g < 8; ++g) sum += red[g][tid];
            l_s[tid] = l_s[tid] * alpha_s[tid] + sum;
        }

#pragma unroll
        for (int r4 = 0; r4 < 4; ++r4) {
            const int row = kr0 + r4 * 16;
            const int j = cs + row;
            float4 v = make_float4(0.f, 0.f, 0.f, 0.f);
            if (j < SEQ)
                v = *(const float4*)&Vm[(size_t)(b * SEQ + j) * ldv + h * HDIM + kc];
            *(float4*)&KVs[row][kc] = v;
        }
        {
            const float al = alpha_s[r];
#pragma unroll
            for (int dd = 0; dd < 8; ++dd) o[dd] *= al;
        }
        __syncthreads();

        for (int j = 0; j < KT; ++j) {
            const float p = Ps[r][j];
            float4 v0 = *(const float4*)&KVs[j][d0];
            float4 v1 = *(const float4*)&KVs[j][d0 + 4];
            o[0] = fmaf(p, v0.x, o[0]);
            o[1] = fmaf(p, v0.y, o[1]);
            o[2] = fmaf(p, v0.z, o[2]);
            o[3] = fmaf(p, v0.w, o[3]);
            o[4] = fmaf(p, v1.x, o[4]);
            o[5] = fmaf(p, v1.y, o[5]);
            o[6] = fmaf(p, v1.z, o[6]);
            o[7] = fmaf(p, v1.w, o[7]);
        }
        __syncthreads();
    }

    const float inv = 1.0f / l_s[r];
    float4 o0, o1;
    o0.x = o[0] * inv; o0.y = o[1] * inv; o0.z = o[2] * inv; o0.w = o[3] * inv;
    o1.x = o[4] * inv; o1.y = o[5] * inv; o1.z = o[6] * inv; o1.w = o[7] * inv;
    float* dst = Om + (size_t)(b * SEQ + q0 + r) * ldo + h * HDIM + d0;
    *(float4*)dst       = o0;
    *(float4*)(dst + 4) = o1;
}

// ---------------------------------------------------------------------------
extern "C" void kernel_launch(void* const* d_in, const int* in_sizes, int n_in,
                              void* d_out, int out_size, void* d_ws, size_t ws_size,
                              hipStream_t stream)
{
    const float* x  = (const float*)d_in[0];
    const float* Wq = (const float*)d_in[1];
    const float* bq = (const float*)d_in[2];
    const float* Wk = (const float*)d_in[3];
    const float* bk = (const float*)d_in[4];
    const float* Wv = (const float*)d_in[5];
    const float* bv = (const float*)d_in[6];
    const float* Wo = (const float*)d_in[7];
    const float* bo = (const float*)d_in[8];
    float* out = (float*)d_out;

    const int M = BATCH * SEQ;                 // 4096
    const size_t MK = (size_t)M * EMB;         // 4M elements

    // MFMA-path ws layout (bytes):
    //   [0,      8.0MiB)  xh   (later: attn fp32 occupies [0,16MiB))
    //   [8MiB,  16.0MiB)  xl
    //   [16MiB, 24.0MiB)  Wcat hi  [4096][1024] bf16
    //   [24MiB, 32.0MiB)  Wcat lo
    //   [32MiB, 64.0MiB)  QKcat fp32 [4096][2048]  (later: attn hi/lo)
    //   [64MiB, +12KiB)   bias_cat fp32 [3072]
    const size_t need = ((size_t)64 << 20) + 16384;

    dim3 blk(256);

    if (ws_size >= need) {
        unsigned short* xh = (unsigned short*)d_ws;
        unsigned short* xl = xh + MK;
        unsigned short* Wh = xl + MK;                  // 4096*1024
        unsigned short* Wl = Wh + (size_t)4096 * EMB;
        float* QK   = (float*)(Wl + (size_t)4096 * EMB);  // [4096][2048]
        float* attn = (float*)d_ws;                    // over xh/xl after QKV
        unsigned short* ath = (unsigned short*)QK;     // over QK after attention
        unsigned short* atl = ath + MK;
        float* bias_cat = (float*)((char*)d_ws + ((size_t)64 << 20));

        // conversions
        hipLaunchKernelGGL(split_bf16_kernel, dim3((int)(MK / (256 * 4))), blk, 0, stream,
                           x, xh, xl, (int)MK);
        hipLaunchKernelGGL(wsplit_t_kernel, dim3(32, 32, 4), blk, 0, stream,
                           Wq, Wk, Wv, Wo, Wh, Wl);
        hipLaunchKernelGGL(bias_cat_kernel, dim3(12), blk, 0, stream, bq, bk, bv, bias_cat);

        // fused QKV GEMM: N=3072; cols<2048 -> QKcat (ld 2048), cols>=2048 -> V in d_out
        hipLaunchKernelGGL(gemm_mfma3_kernel, dim3(24, 32), blk, 0, stream,
                           xh, xl, Wh, Wl, bias_cat,
                           QK, 2048, out, EMB, 2048, EMB);

        // attention: Q = QK cols 0..1023, K = QK cols 1024..2047, V = d_out
        hipLaunchKernelGGL(attn_kernel, dim3(SEQ / QT, BATCH * NHEADS), blk, 0, stream,
                           QK, 2048, QK + 1024, 2048, out, EMB, attn, EMB);

        // convert attention output, final GEMM with Wo^T (rows 3072..4095 of Wcat)
        hipLaunchKernelGGL(split_bf16_kernel, dim3((int)(MK / (256 * 4))), blk, 0, stream,
                           attn, ath, atl, (int)MK);
        hipLaunchKernelGGL(gemm_mfma3_kernel, dim3(8, 32), blk, 0, stream,
                           ath, atl, Wh + (size_t)3072 * EMB, Wl + (size_t)3072 * EMB, bo,
                           out, EMB, out, EMB, 1024, EMB);
    } else {
        // fp32 fallback (round-1 path)
        float* Qb = (float*)d_ws;
        float* Kb = Qb + MK;
        float* Vb = out;
        dim3 ggrid(EMB / BN, M / BM);
        hipLaunchKernelGGL(gemm_bias_kernel, ggrid, blk, 0, stream, x, Wq, bq, Qb, M, EMB, EMB);
        hipLaunchKernelGGL(gemm_bias_kernel, ggrid, blk, 0, stream, x, Wk, bk, Kb, M, EMB, EMB);
        hipLaunchKernelGGL(gemm_bias_kernel, ggrid, blk, 0, stream, x, Wv, bv, Vb, M, EMB, EMB);
        hipLaunchKernelGGL(attn_kernel, dim3(SEQ / QT, BATCH * NHEADS), blk, 0, stream,
                           Qb, EMB, Kb, EMB, Vb, EMB, Qb, EMB);
        hipLaunchKernelGGL(gemm_bias_kernel, ggrid, blk, 0, stream, Qb, Wo, bo, out, M, EMB, EMB);
    }
}

// Round 3
// 292.935 us; speedup vs baseline: 2.5173x; 1.5443x over previous
//
#include <hip/hip_runtime.h>
#include <math.h>
#include <stdint.h>

#define BATCH 2
#define SEQ   2048
#define EMB   1024
#define NHEADS 16
#define HDIM  64
#define WHALF 256      // WINDOW_SIZE/2

typedef __attribute__((ext_vector_type(8))) short short8;
typedef __attribute__((ext_vector_type(4))) float f32x4;

__device__ inline unsigned short f2bf_rn(float x) {
    uint32_t u = __float_as_uint(x);
    u += 0x7FFFu + ((u >> 16) & 1u);
    return (unsigned short)(u >> 16);
}
__device__ inline float bf2f(unsigned short b) {
    return __uint_as_float(((uint32_t)b) << 16);
}

// ---------------------------------------------------------------------------
// split fp32 -> bf16 hi/lo planes
// ---------------------------------------------------------------------------
__global__ __launch_bounds__(256)
void split_bf16_kernel(const float* __restrict__ in, unsigned short* __restrict__ hi,
                       unsigned short* __restrict__ lo, int n)
{
    const int i = (blockIdx.x * 256 + threadIdx.x) * 4;
    if (i >= n) return;
    float4 v = *(const float4*)&in[i];
    ushort4 h, l;
    h.x = f2bf_rn(v.x); l.x = f2bf_rn(v.x - bf2f(h.x));
    h.y = f2bf_rn(v.y); l.y = f2bf_rn(v.y - bf2f(h.y));
    h.z = f2bf_rn(v.z); l.z = f2bf_rn(v.z - bf2f(h.z));
    h.w = f2bf_rn(v.w); l.w = f2bf_rn(v.w - bf2f(h.w));
    *(ushort4*)&hi[i] = h;
    *(ushort4*)&lo[i] = l;
}

// ---------------------------------------------------------------------------
// transpose + split the four 1024x1024 weights into one cat [4096][1024]
// bf16 hi/lo buffer. z==0 (Wq) is pre-scaled by 1/8 (folds QK^T scale).
// ---------------------------------------------------------------------------
__global__ __launch_bounds__(256)
void wsplit_t_kernel(const float* __restrict__ W0, const float* __restrict__ W1,
                     const float* __restrict__ W2, const float* __restrict__ W3,
                     unsigned short* __restrict__ hi, unsigned short* __restrict__ lo)
{
    __shared__ float t[32][33];
    const float* W = (blockIdx.z == 0) ? W0 : (blockIdx.z == 1) ? W1
                   : (blockIdx.z == 2) ? W2 : W3;
    const float scale = (blockIdx.z == 0) ? 0.125f : 1.0f;
    const int n0 = blockIdx.x * 32;
    const int k0 = blockIdx.y * 32;
    const int tx = threadIdx.x & 31, ty = threadIdx.x >> 5;
#pragma unroll
    for (int i = 0; i < 4; ++i)
        t[ty + i * 8][tx] = W[(size_t)(k0 + ty + i * 8) * EMB + n0 + tx];
    __syncthreads();
#pragma unroll
    for (int i = 0; i < 4; ++i) {
        float v = t[tx][ty + i * 8] * scale;
        unsigned short h = f2bf_rn(v);
        unsigned short l = f2bf_rn(v - bf2f(h));
        size_t o = (size_t)(blockIdx.z * EMB + n0 + ty + i * 8) * EMB + k0 + tx;
        hi[o] = h; lo[o] = l;
    }
}

__global__ __launch_bounds__(256)
void bias_cat_kernel(const float* __restrict__ bq, const float* __restrict__ bk,
                     const float* __restrict__ bv, float* __restrict__ out)
{
    const int i = blockIdx.x * 256 + threadIdx.x;
    if (i < 1024)      out[i] = bq[i] * 0.125f;
    else if (i < 2048) out[i] = bk[i - 1024];
    else if (i < 3072) out[i] = bv[i - 2048];
}

// ---------------------------------------------------------------------------
// bf16x3 MFMA GEMM: C = (Ah+Al) @ (Bh+Bl)^T + bias  (drop Al*Bl term)
// A: [M][K] bf16 hi/lo.  B: [N][K] bf16 hi/lo (pre-transposed).
// 128x128 tile, BK=32. Output fp32 or bf16 (template).
// ---------------------------------------------------------------------------
#define GLDS(gp, lp) __builtin_amdgcn_global_load_lds(                       \
    (const __attribute__((address_space(1))) void*)(gp),                     \
    (__attribute__((address_space(3))) void*)(lp), 16, 0, 0)

template<bool BF16OUT>
__global__ __launch_bounds__(256)
void gemm_mfma3_kernel(const unsigned short* __restrict__ Ah,
                       const unsigned short* __restrict__ Al,
                       const unsigned short* __restrict__ Bh,
                       const unsigned short* __restrict__ Bl,
                       const float* __restrict__ bias,
                       void* __restrict__ Cv, int ldc, int K)
{
    __shared__ unsigned short sAh[128 * 32], sAl[128 * 32];
    __shared__ unsigned short sBh[128 * 32], sBl[128 * 32];

    const int tid = threadIdx.x;
    const int l = tid & 63;
    const int w = tid >> 6;
    const int wm = w >> 1, wn = w & 1;
    const int row0 = blockIdx.y * 128;
    const int col0 = blockIdx.x * 128;

    f32x4 acc[4][4] = {};

    const int sr = tid >> 2;
    const int sk = (tid & 3) * 8;
    const unsigned short* pAh = Ah + (size_t)(row0 + sr) * K + sk;
    const unsigned short* pAl = Al + (size_t)(row0 + sr) * K + sk;
    const unsigned short* pBh = Bh + (size_t)(col0 + sr) * K + sk;
    const unsigned short* pBl = Bl + (size_t)(col0 + sr) * K + sk;
    const size_t rstep = (size_t)64 * K;

    const int kq = (l >> 4) * 8;
    const int lr = l & 15;

    for (int k0 = 0; k0 < K; k0 += 32) {
        GLDS(pAh + k0,         &sAh[tid * 8]);
        GLDS(pAh + rstep + k0, &sAh[2048 + tid * 8]);
        GLDS(pAl + k0,         &sAl[tid * 8]);
        GLDS(pAl + rstep + k0, &sAl[2048 + tid * 8]);
        GLDS(pBh + k0,         &sBh[tid * 8]);
        GLDS(pBh + rstep + k0, &sBh[2048 + tid * 8]);
        GLDS(pBl + k0,         &sBl[tid * 8]);
        GLDS(pBl + rstep + k0, &sBl[2048 + tid * 8]);
        __syncthreads();

        short8 ah[4], al[4], bh[4], bl[4];
#pragma unroll
        for (int f = 0; f < 4; ++f) {
            ah[f] = *(const short8*)&sAh[(wm * 64 + f * 16 + lr) * 32 + kq];
            al[f] = *(const short8*)&sAl[(wm * 64 + f * 16 + lr) * 32 + kq];
            bh[f] = *(const short8*)&sBh[(wn * 64 + f * 16 + lr) * 32 + kq];
            bl[f] = *(const short8*)&sBl[(wn * 64 + f * 16 + lr) * 32 + kq];
        }
#pragma unroll
        for (int mf = 0; mf < 4; ++mf)
#pragma unroll
            for (int nf = 0; nf < 4; ++nf) {
                acc[mf][nf] = __builtin_amdgcn_mfma_f32_16x16x32_bf16(ah[mf], bh[nf], acc[mf][nf], 0, 0, 0);
                acc[mf][nf] = __builtin_amdgcn_mfma_f32_16x16x32_bf16(ah[mf], bl[nf], acc[mf][nf], 0, 0, 0);
                acc[mf][nf] = __builtin_amdgcn_mfma_f32_16x16x32_bf16(al[mf], bh[nf], acc[mf][nf], 0, 0, 0);
            }
        __syncthreads();
    }

    const int lq = l >> 4;
#pragma unroll
    for (int nf = 0; nf < 4; ++nf) {
        const int c = wn * 64 + nf * 16 + lr;
        const float bv = bias[col0 + c];
#pragma unroll
        for (int mf = 0; mf < 4; ++mf) {
            const int r = row0 + wm * 64 + mf * 16 + lq * 4;
#pragma unroll
            for (int i = 0; i < 4; ++i) {
                const float val = acc[mf][nf][i] + bv;
                if (BF16OUT)
                    ((unsigned short*)Cv)[(size_t)(r + i) * ldc + col0 + c] = f2bf_rn(val);
                else
                    ((float*)Cv)[(size_t)(r + i) * ldc + col0 + c] = val;
            }
        }
    }
}

// ---------------------------------------------------------------------------
// MFMA sliding-window flash attention, all-bf16 inputs.
// QKV: [B*SEQ][3072] bf16 cat buffer (Q pre-scaled by 1/8 | K | V).
// Block: 256 thr = 4 waves; 64-query tile; 64-key chunks; online softmax in
// registers via 16-lane shuffles. Output: bf16 hi/lo planes [B*SEQ][1024].
// Grid: 1024 blocks 1D, gid&7 = XCD slot (4 heads/XCD -> K/V fits 4MB L2).
// ---------------------------------------------------------------------------
#define AP 66   // padded LDS row stride (shorts)

__global__ __launch_bounds__(256)
void attn_mfma_kernel(const unsigned short* __restrict__ QKV,
                      unsigned short* __restrict__ Oh,
                      unsigned short* __restrict__ Ol)
{
    __shared__ unsigned short Qs[64 * AP], Ks[64 * AP], Vt[64 * AP], Ps[64 * AP];

    const int tid = threadIdx.x;
    const int gid = blockIdx.x;
    const int X = gid & 7, rest = gid >> 3;
    const int hg = rest & 3, tile = rest >> 2;
    const int bh = X * 4 + hg;
    const int b = bh >> 4, h = bh & 15;
    const int q0 = tile * 64;

    const int l = tid & 63, w = tid >> 6;
    const int lr = l & 15, g = l >> 4;

    const size_t rowbase = (size_t)b * SEQ;
    const unsigned short* Qg = QKV + h * HDIM;
    const unsigned short* Kg = QKV + 1024 + h * HDIM;
    const unsigned short* Vg = QKV + 2048 + h * HDIM;

    // stage Q tile
    {
        const int r = tid >> 2, sg = (tid & 3) * 16;
        const unsigned short* src = Qg + (rowbase + q0 + r) * 3072 + sg;
        *(short8*)&Qs[r * AP + sg]     = *(const short8*)src;
        *(short8*)&Qs[r * AP + sg + 8] = *(const short8*)(src + 8);
    }
    __syncthreads();

    short8 qa0 = *(const short8*)&Qs[(w * 16 + lr) * AP + g * 8];
    short8 qa1 = *(const short8*)&Qs[(w * 16 + lr) * AP + 32 + g * 8];

    f32x4 o[4] = {};
    float m_[4], l_[4];
#pragma unroll
    for (int i = 0; i < 4; ++i) { m_[i] = -1e30f; l_[i] = 0.0f; }

    const int c_begin = (q0 >= WHALF) ? 0 : (WHALF - q0) >> 6;
    int c_end = (SEQ + 192 - q0) >> 6; if (c_end > 8) c_end = 8;

    for (int c = c_begin; c <= c_end; ++c) {
        const int cs = q0 - WHALF + c * 64;

        // stage K chunk + V chunk (transposed)
        {
            const int r = tid >> 2, sg = (tid & 3) * 16;
            const unsigned short* ks = Kg + (rowbase + cs + r) * 3072 + sg;
            *(short8*)&Ks[r * AP + sg]     = *(const short8*)ks;
            *(short8*)&Ks[r * AP + sg + 8] = *(const short8*)(ks + 8);
            const unsigned short* vs = Vg + (rowbase + cs + r) * 3072 + sg;
            short8 v0 = *(const short8*)vs;
            short8 v1 = *(const short8*)(vs + 8);
#pragma unroll
            for (int i2 = 0; i2 < 8; ++i2) Vt[(sg + i2) * AP + r]     = v0[i2];
#pragma unroll
            for (int i2 = 0; i2 < 8; ++i2) Vt[(sg + 8 + i2) * AP + r] = v1[i2];
        }
        __syncthreads();

        // ---- QK^T : scores [16q x 64k] per wave, C layout ----
        f32x4 sc[4] = {};
#pragma unroll
        for (int kf = 0; kf < 4; ++kf) {
            short8 b0 = *(const short8*)&Ks[(kf * 16 + lr) * AP + g * 8];
            short8 b1 = *(const short8*)&Ks[(kf * 16 + lr) * AP + 32 + g * 8];
            sc[kf] = __builtin_amdgcn_mfma_f32_16x16x32_bf16(qa0, b0, sc[kf], 0, 0, 0);
            sc[kf] = __builtin_amdgcn_mfma_f32_16x16x32_bf16(qa1, b1, sc[kf], 0, 0, 0);
        }

        // ---- window mask (only edge chunks) ----
        if (c == 0) {
#pragma unroll
            for (int kf = 0; kf < 4; ++kf) {
                const int j = cs + kf * 16 + lr;
#pragma unroll
                for (int i = 0; i < 4; ++i) {
                    const int q = q0 + w * 16 + g * 4 + i;
                    if (j < q - WHALF) sc[kf][i] = -1e30f;
                }
            }
        } else if (c == 8) {
#pragma unroll
            for (int kf = 0; kf < 4; ++kf) {
                const int j = cs + kf * 16 + lr;
#pragma unroll
                for (int i = 0; i < 4; ++i) {
                    const int q = q0 + w * 16 + g * 4 + i;
                    if (j > q + WHALF) sc[kf][i] = -1e30f;
                }
            }
        }

        // ---- online softmax: row stats via 16-lane shuffle reduce ----
        float cm[4], alpha[4], rs[4];
#pragma unroll
        for (int i = 0; i < 4; ++i) {
            float v = fmaxf(fmaxf(sc[0][i], sc[1][i]), fmaxf(sc[2][i], sc[3][i]));
            v = fmaxf(v, __shfl_xor(v, 1));
            v = fmaxf(v, __shfl_xor(v, 2));
            v = fmaxf(v, __shfl_xor(v, 4));
            v = fmaxf(v, __shfl_xor(v, 8));
            cm[i] = v;
        }
#pragma unroll
        for (int i = 0; i < 4; ++i) {
            const float mn = fmaxf(fmaxf(m_[i], cm[i]), -1e4f);
            alpha[i] = __expf(m_[i] - mn);
            m_[i] = mn;
            rs[i] = 0.0f;
        }
#pragma unroll
        for (int kf = 0; kf < 4; ++kf)
#pragma unroll
            for (int i = 0; i < 4; ++i) {
                const float p = __expf(sc[kf][i] - m_[i]);
                rs[i] += p;
                Ps[(w * 16 + g * 4 + i) * AP + kf * 16 + lr] = f2bf_rn(p);
            }
#pragma unroll
        for (int i = 0; i < 4; ++i) {
            float v = rs[i];
            v += __shfl_xor(v, 1);
            v += __shfl_xor(v, 2);
            v += __shfl_xor(v, 4);
            v += __shfl_xor(v, 8);
            l_[i] = l_[i] * alpha[i] + v;
        }
#pragma unroll
        for (int df = 0; df < 4; ++df)
#pragma unroll
            for (int i = 0; i < 4; ++i) o[df][i] *= alpha[i];

        // ---- P @ V ----  (Ps rows are wave-private; Vt synced above)
        short8 pa0 = *(const short8*)&Ps[(w * 16 + lr) * AP + g * 8];
        short8 pa1 = *(const short8*)&Ps[(w * 16 + lr) * AP + 32 + g * 8];
#pragma unroll
        for (int df = 0; df < 4; ++df) {
            short8 vb0 = *(const short8*)&Vt[(df * 16 + lr) * AP + g * 8];
            short8 vb1 = *(const short8*)&Vt[(df * 16 + lr) * AP + 32 + g * 8];
            o[df] = __builtin_amdgcn_mfma_f32_16x16x32_bf16(pa0, vb0, o[df], 0, 0, 0);
            o[df] = __builtin_amdgcn_mfma_f32_16x16x32_bf16(pa1, vb1, o[df], 0, 0, 0);
        }
        __syncthreads();   // Ks/Vt reads done before next chunk's staging
    }

    // ---- epilogue: normalize, split to bf16 hi/lo ----
    float inv[4];
#pragma unroll
    for (int i = 0; i < 4; ++i) inv[i] = 1.0f / l_[i];
#pragma unroll
    for (int df = 0; df < 4; ++df)
#pragma unroll
        for (int i = 0; i < 4; ++i) {
            const float v = o[df][i] * inv[i];
            const unsigned short hb = f2bf_rn(v);
            const unsigned short lb = f2bf_rn(v - bf2f(hb));
            const size_t off = (rowbase + q0 + w * 16 + g * 4 + i) * 1024
                             + h * HDIM + df * 16 + lr;
            Oh[off] = hb; Ol[off] = lb;
        }
}

// ---------------------------------------------------------------------------
// fp32 fallback GEMM + attention (only if ws too small)
// ---------------------------------------------------------------------------
#define BM 64
#define BN 64
#define BK 16

__global__ __launch_bounds__(256)
void gemm_bias_kernel(const float* __restrict__ A, const float* __restrict__ W,
                      const float* __restrict__ bias, float* __restrict__ C,
                      int M, int N, int K)
{
    __shared__ float As[BK][BM + 4];
    __shared__ float Bs[BK][BN + 4];
    const int tid = threadIdx.x;
    const int tx = tid & 15, ty = tid >> 4;
    const int row0 = blockIdx.y * BM;
    const int col0 = blockIdx.x * BN;
    float acc[4][4] = {};
    const int ar = tid >> 2;
    const int ak = (tid & 3) * 4;
    const int br = tid >> 4;
    const int bc = (tid & 15) * 4;
    for (int k0 = 0; k0 < K; k0 += BK) {
        float4 a = *(const float4*)&A[(size_t)(row0 + ar) * K + k0 + ak];
        float4 b = *(const float4*)&W[(size_t)(k0 + br) * N + col0 + bc];
        As[ak + 0][ar] = a.x; As[ak + 1][ar] = a.y;
        As[ak + 2][ar] = a.z; As[ak + 3][ar] = a.w;
        *(float4*)&Bs[br][bc] = b;
        __syncthreads();
#pragma unroll
        for (int kk = 0; kk < BK; ++kk) {
            float4 av = *(const float4*)&As[kk][ty * 4];
            float4 bv = *(const float4*)&Bs[kk][tx * 4];
            float aa[4] = {av.x, av.y, av.z, av.w};
            float bb[4] = {bv.x, bv.y, bv.z, bv.w};
#pragma unroll
            for (int i = 0; i < 4; ++i)
#pragma unroll
                for (int j = 0; j < 4; ++j)
                    acc[i][j] = fmaf(aa[i], bb[j], acc[i][j]);
        }
        __syncthreads();
    }
    const float4 bvec = *(const float4*)&bias[col0 + tx * 4];
    const float bb[4] = {bvec.x, bvec.y, bvec.z, bvec.w};
#pragma unroll
    for (int i = 0; i < 4; ++i) {
        float4 oo;
        oo.x = acc[i][0] + bb[0]; oo.y = acc[i][1] + bb[1];
        oo.z = acc[i][2] + bb[2]; oo.w = acc[i][3] + bb[3];
        *(float4*)&C[(size_t)(row0 + ty * 4 + i) * N + col0 + tx * 4] = oo;
    }
}

#define QT 32
#define KT 64

__global__ __launch_bounds__(256)
void attn_kernel(const float* __restrict__ Qm, int ldq,
                 const float* __restrict__ Km, int ldk,
                 const float* __restrict__ Vm, int ldv,
                 float* __restrict__ Om, int ldo)
{
    __shared__ float Qs[QT][HDIM + 4];
    __shared__ float KVs[KT][HDIM + 4];
    __shared__ float Ps[QT][KT + 1];
    __shared__ float red[8][QT];
    __shared__ float m_s[QT], l_s[QT], alpha_s[QT];
    const int tid = threadIdx.x;
    const int b  = blockIdx.y / NHEADS;
    const int h  = blockIdx.y % NHEADS;
    const int q0 = blockIdx.x * QT;
    const int r  = tid & 31;
    const int cg = tid >> 5;
    const int d0 = cg * 8;
    {
        const int qr = tid >> 3;
        const int qd = (tid & 7) * 8;
        const float* src = Qm + (size_t)(b * SEQ + q0 + qr) * ldq + h * HDIM + qd;
        *(float4*)&Qs[qr][qd]     = *(const float4*)(src);
        *(float4*)&Qs[qr][qd + 4] = *(const float4*)(src + 4);
    }
    if (tid < QT) { m_s[tid] = -1e30f; l_s[tid] = 0.0f; }
    __syncthreads();
    float qreg[HDIM];
#pragma unroll
    for (int d4 = 0; d4 < HDIM; d4 += 4) {
        float4 t = *(const float4*)&Qs[r][d4];
        qreg[d4] = t.x; qreg[d4 + 1] = t.y; qreg[d4 + 2] = t.z; qreg[d4 + 3] = t.w;
    }
    float o[8] = {};
    const int iq = q0 + r;
    int lo = q0 - WHALF; if (lo < 0) lo = 0;
    const int cs0 = lo & ~(KT - 1);
    int hi = q0 + QT + WHALF; if (hi > SEQ) hi = SEQ;
    const int nch = (hi - cs0 + KT - 1) / KT;
    const int kr0 = tid >> 4;
    const int kc  = (tid & 15) * 4;
    for (int ch = 0; ch < nch; ++ch) {
        const int cs = cs0 + ch * KT;
#pragma unroll
        for (int r4 = 0; r4 < 4; ++r4) {
            const int row = kr0 + r4 * 16;
            const int j = cs + row;
            float4 v = make_float4(0.f, 0.f, 0.f, 0.f);
            if (j < SEQ)
                v = *(const float4*)&Km[(size_t)(b * SEQ + j) * ldk + h * HDIM + kc];
            *(float4*)&KVs[row][kc] = v;
        }
        __syncthreads();
        float s[8];
#pragma unroll
        for (int cc = 0; cc < 8; ++cc) {
            const int cidx = d0 + cc;
            float acc = 0.0f;
#pragma unroll
            for (int d4 = 0; d4 < HDIM; d4 += 4) {
                float4 kv = *(const float4*)&KVs[cidx][d4];
                acc = fmaf(qreg[d4],     kv.x, acc);
                acc = fmaf(qreg[d4 + 1], kv.y, acc);
                acc = fmaf(qreg[d4 + 2], kv.z, acc);
                acc = fmaf(qreg[d4 + 3], kv.w, acc);
            }
            const int j = cs + cidx;
            const bool valid = (j < SEQ) && (j >= iq - WHALF) && (j <= iq + WHALF);
            s[cc] = valid ? acc * 0.125f : -1e30f;
        }
        float lm = s[0];
#pragma unroll
        for (int cc = 1; cc < 8; ++cc) lm = fmaxf(lm, s[cc]);
        red[cg][r] = lm;
        __syncthreads();
        if (tid < QT) {
            float m = m_s[tid];
            float mc = red[0][tid];
#pragma unroll
            for (int g2 = 1; g2 < 8; ++g2) mc = fmaxf(mc, red[g2][tid]);
            const float mn = fmaxf(m, mc);
            alpha_s[tid] = __expf(m - mn);
            m_s[tid] = mn;
        }
        __syncthreads();
        const float mn = m_s[r];
        float ls = 0.0f;
#pragma unroll
        for (int cc = 0; cc < 8; ++cc) {
            const float p = __expf(s[cc] - mn);
            Ps[r][d0 + cc] = p;
            ls += p;
        }
        red[cg][r] = ls;
        __syncthreads();
        if (tid < QT) {
            float sum = red[0][tid];
#pragma unroll
            for (int g2 = 1; g2 < 8; ++g2) sum += red[g2][tid];
            l_s[tid] = l_s[tid] * alpha_s[tid] + sum;
        }
#pragma unroll
        for (int r4 = 0; r4 < 4; ++r4) {
            const int row = kr0 + r4 * 16;
            const int j = cs + row;
            float4 v = make_float4(0.f, 0.f, 0.f, 0.f);
            if (j < SEQ)
                v = *(const float4*)&Vm[(size_t)(b * SEQ + j) * ldv + h * HDIM + kc];
            *(float4*)&KVs[row][kc] = v;
        }
        {
            const float al = alpha_s[r];
#pragma unroll
            for (int dd = 0; dd < 8; ++dd) o[dd] *= al;
        }
        __syncthreads();
        for (int j = 0; j < KT; ++j) {
            const float p = Ps[r][j];
            float4 v0 = *(const float4*)&KVs[j][d0];
            float4 v1 = *(const float4*)&KVs[j][d0 + 4];
            o[0] = fmaf(p, v0.x, o[0]); o[1] = fmaf(p, v0.y, o[1]);
            o[2] = fmaf(p, v0.z, o[2]); o[3] = fmaf(p, v0.w, o[3]);
            o[4] = fmaf(p, v1.x, o[4]); o[5] = fmaf(p, v1.y, o[5]);
            o[6] = fmaf(p, v1.z, o[6]); o[7] = fmaf(p, v1.w, o[7]);
        }
        __syncthreads();
    }
    const float inv = 1.0f / l_s[r];
    float4 o0, o1;
    o0.x = o[0] * inv; o0.y = o[1] * inv; o0.z = o[2] * inv; o0.w = o[3] * inv;
    o1.x = o[4] * inv; o1.y = o[5] * inv; o1.z = o[6] * inv; o1.w = o[7] * inv;
    float* dst = Om + (size_t)(b * SEQ + q0 + r) * ldo + h * HDIM + d0;
    *(float4*)dst       = o0;
    *(float4*)(dst + 4) = o1;
}

// ---------------------------------------------------------------------------
extern "C" void kernel_launch(void* const* d_in, const int* in_sizes, int n_in,
                              void* d_out, int out_size, void* d_ws, size_t ws_size,
                              hipStream_t stream)
{
    const float* x  = (const float*)d_in[0];
    const float* Wq = (const float*)d_in[1];
    const float* bq = (const float*)d_in[2];
    const float* Wk = (const float*)d_in[3];
    const float* bk = (const float*)d_in[4];
    const float* Wv = (const float*)d_in[5];
    const float* bv = (const float*)d_in[6];
    const float* Wo = (const float*)d_in[7];
    const float* bo = (const float*)d_in[8];
    float* out = (float*)d_out;

    const int M = BATCH * SEQ;                 // 4096
    const size_t MK = (size_t)M * EMB;         // 4M elements

    const size_t need = ((size_t)64 << 20) + 16384;
    dim3 blk(256);

    if (ws_size >= need) {
        // ws layout:
        //  [0,8M)    Wh        [8M,16M)  Wl
        //  [16M,24M) xh -> ath [24M,32M) xl -> atl   (reused after QKV GEMM)
        //  [32M,56M) QKVb bf16 [4096][3072]
        //  [56M,+12K) bias_cat
        unsigned short* Wh = (unsigned short*)d_ws;
        unsigned short* Wl = Wh + (size_t)4096 * EMB;
        unsigned short* xh = Wl + (size_t)4096 * EMB;
        unsigned short* xl = xh + MK;
        unsigned short* QKVb = xl + MK;
        unsigned short* ath = xh;     // reuse after QKV GEMM consumed x
        unsigned short* atl = xl;
        float* bias_cat = (float*)((char*)d_ws + ((size_t)56 << 20));

        hipLaunchKernelGGL(split_bf16_kernel, dim3((int)(MK / (256 * 4))), blk, 0, stream,
                           x, xh, xl, (int)MK);
        hipLaunchKernelGGL(wsplit_t_kernel, dim3(32, 32, 4), blk, 0, stream,
                           Wq, Wk, Wv, Wo, Wh, Wl);
        hipLaunchKernelGGL(bias_cat_kernel, dim3(12), blk, 0, stream, bq, bk, bv, bias_cat);

        // fused QKV GEMM -> bf16 cat buffer [4096][3072]
        hipLaunchKernelGGL((gemm_mfma3_kernel<true>), dim3(24, 32), blk, 0, stream,
                           xh, xl, Wh, Wl, bias_cat, (void*)QKVb, 3072, EMB);

        // MFMA flash attention -> bf16 hi/lo planes
        hipLaunchKernelGGL(attn_mfma_kernel, dim3(1024), blk, 0, stream,
                           QKVb, ath, atl);

        // final GEMM: attn @ Wo + bo -> fp32 out
        hipLaunchKernelGGL((gemm_mfma3_kernel<false>), dim3(8, 32), blk, 0, stream,
                           ath, atl, Wh + (size_t)3072 * EMB, Wl + (size_t)3072 * EMB, bo,
                           (void*)out, EMB, EMB);
    } else {
        float* Qb = (float*)d_ws;
        float* Kb = Qb + MK;
        float* Vb = out;
        dim3 ggrid(EMB / BN, M / BM);
        hipLaunchKernelGGL(gemm_bias_kernel, ggrid, blk, 0, stream, x, Wq, bq, Qb, M, EMB, EMB);
        hipLaunchKernelGGL(gemm_bias_kernel, ggrid, blk, 0, stream, x, Wk, bk, Kb, M, EMB, EMB);
        hipLaunchKernelGGL(gemm_bias_kernel, ggrid, blk, 0, stream, x, Wv, bv, Vb, M, EMB, EMB);
        hipLaunchKernelGGL(attn_kernel, dim3(SEQ / QT, BATCH * NHEADS), blk, 0, stream,
                           Qb, EMB, Kb, EMB, Vb, EMB, Qb, EMB);
        hipLaunchKernelGGL(gemm_bias_kernel, ggrid, blk, 0, stream, Qb, Wo, bo, out, M, EMB, EMB);
    }
}

// Round 4
// 208.606 us; speedup vs baseline: 3.5349x; 1.4042x over previous
//
#include <hip/hip_runtime.h>
#include <math.h>
#include <stdint.h>

#define BATCH 2
#define SEQ   2048
#define EMB   1024
#define NHEADS 16
#define HDIM  64
#define WHALF 256      // WINDOW_SIZE/2

typedef __attribute__((ext_vector_type(8))) short short8;
typedef __attribute__((ext_vector_type(8))) _Float16 half8;
typedef __attribute__((ext_vector_type(4))) _Float16 half4;
typedef __attribute__((ext_vector_type(4))) float f32x4;

// ---------------------------------------------------------------------------
// cast fp32 -> fp16 (8 per thread)
// ---------------------------------------------------------------------------
__global__ __launch_bounds__(256)
void cast16_kernel(const float* __restrict__ in, unsigned short* __restrict__ o16, int n)
{
    const int i = (blockIdx.x * 256 + threadIdx.x) * 8;
    if (i >= n) return;
    float4 v0 = *(const float4*)&in[i];
    float4 v1 = *(const float4*)&in[i + 4];
    half8 h;
    h[0] = (_Float16)v0.x; h[1] = (_Float16)v0.y;
    h[2] = (_Float16)v0.z; h[3] = (_Float16)v0.w;
    h[4] = (_Float16)v1.x; h[5] = (_Float16)v1.y;
    h[6] = (_Float16)v1.z; h[7] = (_Float16)v1.w;
    *(half8*)&o16[i] = h;
}

// ---------------------------------------------------------------------------
// transpose + cast the four 1024x1024 weights into one cat [4096][1024] fp16
// buffer (Wq^T/8 | Wk^T | Wv^T | Wo^T).
// ---------------------------------------------------------------------------
__global__ __launch_bounds__(256)
void wsplit16_t_kernel(const float* __restrict__ W0, const float* __restrict__ W1,
                       const float* __restrict__ W2, const float* __restrict__ W3,
                       unsigned short* __restrict__ o16)
{
    __shared__ float t[32][33];
    const float* W = (blockIdx.z == 0) ? W0 : (blockIdx.z == 1) ? W1
                   : (blockIdx.z == 2) ? W2 : W3;
    const float scale = (blockIdx.z == 0) ? 0.125f : 1.0f;
    const int n0 = blockIdx.x * 32;
    const int k0 = blockIdx.y * 32;
    const int tx = threadIdx.x & 31, ty = threadIdx.x >> 5;
#pragma unroll
    for (int i = 0; i < 4; ++i)
        t[ty + i * 8][tx] = W[(size_t)(k0 + ty + i * 8) * EMB + n0 + tx];
    __syncthreads();
#pragma unroll
    for (int i = 0; i < 4; ++i) {
        float v = t[tx][ty + i * 8] * scale;
        size_t o = (size_t)(blockIdx.z * EMB + n0 + ty + i * 8) * EMB + k0 + tx;
        *(_Float16*)&o16[o] = (_Float16)v;
    }
}

__global__ __launch_bounds__(256)
void bias_cat_kernel(const float* __restrict__ bq, const float* __restrict__ bk,
                     const float* __restrict__ bv, float* __restrict__ out)
{
    const int i = blockIdx.x * 256 + threadIdx.x;
    if (i < 1024)      out[i] = bq[i] * 0.125f;
    else if (i < 2048) out[i] = bk[i - 1024];
    else if (i < 3072) out[i] = bv[i - 2048];
}

// ---------------------------------------------------------------------------
// fp16 MFMA GEMM: C = A @ B^T + bias.  A: [M][K] fp16, B: [N][K] fp16.
// 128x128 tile, BK=32, 256 thr = 4 waves (2x2), 4x4 16x16x32 frags/wave.
// MODE 0: C0 = fp32 [M][ldc].
// MODE 1 (QKV): cols<2048 -> QKb fp16 [M][2048]; cols>=2048 -> Vt fp16
//               transposed [(b*1024 + vcol)][2048] (vcol = h*64+d).
// ---------------------------------------------------------------------------
#define GLDS(gp, lp) __builtin_amdgcn_global_load_lds(                       \
    (const __attribute__((address_space(1))) void*)(gp),                     \
    (__attribute__((address_space(3))) void*)(lp), 16, 0, 0)

template<int MODE>
__global__ __launch_bounds__(256)
void gemm_f16_kernel(const unsigned short* __restrict__ A,
                     const unsigned short* __restrict__ B,
                     const float* __restrict__ bias,
                     void* __restrict__ C0, void* __restrict__ C1,
                     int ldc, int K)
{
    __shared__ unsigned short sA[128 * 32], sB[128 * 32];

    const int tid = threadIdx.x;
    const int l = tid & 63;
    const int w = tid >> 6;
    const int wm = w >> 1, wn = w & 1;
    const int row0 = blockIdx.y * 128;
    const int col0 = blockIdx.x * 128;

    f32x4 acc[4][4] = {};

    const int sr = tid >> 2;
    const int sk = (tid & 3) * 8;
    const unsigned short* pA = A + (size_t)(row0 + sr) * K + sk;
    const unsigned short* pB = B + (size_t)(col0 + sr) * K + sk;
    const size_t rstep = (size_t)64 * K;

    const int kq = (l >> 4) * 8;
    const int lr = l & 15;

    for (int k0 = 0; k0 < K; k0 += 32) {
        GLDS(pA + k0,         &sA[tid * 8]);
        GLDS(pA + rstep + k0, &sA[2048 + tid * 8]);
        GLDS(pB + k0,         &sB[tid * 8]);
        GLDS(pB + rstep + k0, &sB[2048 + tid * 8]);
        __syncthreads();

        half8 af[4], bf[4];
#pragma unroll
        for (int f = 0; f < 4; ++f) {
            af[f] = *(const half8*)&sA[(wm * 64 + f * 16 + lr) * 32 + kq];
            bf[f] = *(const half8*)&sB[(wn * 64 + f * 16 + lr) * 32 + kq];
        }
#pragma unroll
        for (int mf = 0; mf < 4; ++mf)
#pragma unroll
            for (int nf = 0; nf < 4; ++nf)
                acc[mf][nf] = __builtin_amdgcn_mfma_f32_16x16x32_f16(af[mf], bf[nf], acc[mf][nf], 0, 0, 0);
        __syncthreads();
    }

    // epilogue: C/D layout col=lane&15, row=(lane>>4)*4+reg
    const int lq = l >> 4;
#pragma unroll
    for (int nf = 0; nf < 4; ++nf) {
        const int c = wn * 64 + nf * 16 + lr;
        const float bv = bias[col0 + c];
#pragma unroll
        for (int mf = 0; mf < 4; ++mf) {
            const int r = row0 + wm * 64 + mf * 16 + lq * 4;
            if (MODE == 0) {
#pragma unroll
                for (int i = 0; i < 4; ++i)
                    ((float*)C0)[(size_t)(r + i) * ldc + col0 + c] = acc[mf][nf][i] + bv;
            } else if (col0 < 2048) {
#pragma unroll
                for (int i = 0; i < 4; ++i)
                    ((_Float16*)C0)[(size_t)(r + i) * 2048 + col0 + c] =
                        (_Float16)(acc[mf][nf][i] + bv);
            } else {
                half4 pk;
#pragma unroll
                for (int i = 0; i < 4; ++i) pk[i] = (_Float16)(acc[mf][nf][i] + bv);
                const int vb = r >> 11, s = r & 2047;
                *(half4*)((_Float16*)C1 + ((size_t)(vb * 1024 + (col0 - 2048 + c))) * 2048 + s) = pk;
            }
        }
    }
}

// ---------------------------------------------------------------------------
// fp16 MFMA sliding-window flash attention.
// QKb: [B*S][2048] fp16 (Q/8 | K).  Vt: [(b*1024+h*64+d)][2048] fp16 (V^T).
// 256 thr = 4 waves; 64-q tile; 64-key chunks; online softmax in registers.
// Output: fp16 [B*S][1024].  Grid 1024, gid&7 = XCD slot.
// ---------------------------------------------------------------------------
#define AP 66   // padded LDS row stride (shorts)

__global__ __launch_bounds__(256)
void attn_f16_kernel(const unsigned short* __restrict__ QKb,
                     const unsigned short* __restrict__ Vt,
                     unsigned short* __restrict__ Oa)
{
    __shared__ unsigned short Qs[64 * AP], Ks[64 * AP], Vs[64 * AP], Ps[64 * AP];

    const int tid = threadIdx.x;
    const int gid = blockIdx.x;
    const int X = gid & 7, rest = gid >> 3;
    const int hg = rest & 3, tile = rest >> 2;
    const int bh = X * 4 + hg;
    const int b = bh >> 4, h = bh & 15;
    const int q0 = tile * 64;

    const int l = tid & 63, w = tid >> 6;
    const int lr = l & 15, g = l >> 4;

    const size_t rowbase = (size_t)b * SEQ;

    // stage Q tile
    {
        const int r = tid >> 2, sg = (tid & 3) * 16;
        const unsigned short* src = QKb + (rowbase + q0 + r) * 2048 + h * HDIM + sg;
        *(short8*)&Qs[r * AP + sg]     = *(const short8*)src;
        *(short8*)&Qs[r * AP + sg + 8] = *(const short8*)(src + 8);
    }
    __syncthreads();

    half8 qa0 = *(const half8*)&Qs[(w * 16 + lr) * AP + g * 8];
    half8 qa1 = *(const half8*)&Qs[(w * 16 + lr) * AP + 32 + g * 8];

    f32x4 o[4] = {};
    float m_[4], l_[4];
#pragma unroll
    for (int i = 0; i < 4; ++i) { m_[i] = -1e30f; l_[i] = 0.0f; }

    const int c_begin = (q0 >= WHALF) ? 0 : (WHALF - q0) >> 6;
    int c_end = (SEQ + 192 - q0) >> 6; if (c_end > 8) c_end = 8;

    for (int c = c_begin; c <= c_end; ++c) {
        const int cs = q0 - WHALF + c * 64;

        // stage K chunk + V^T chunk (both vectorized)
        {
            const int r = tid >> 2, sg = (tid & 3) * 16;
            const unsigned short* ks = QKb + (rowbase + cs + r) * 2048 + 1024 + h * HDIM + sg;
            *(short8*)&Ks[r * AP + sg]     = *(const short8*)ks;
            *(short8*)&Ks[r * AP + sg + 8] = *(const short8*)(ks + 8);
            const unsigned short* vs = Vt + ((size_t)(b * 1024 + h * HDIM + r)) * 2048 + cs + sg;
            *(short8*)&Vs[r * AP + sg]     = *(const short8*)vs;
            *(short8*)&Vs[r * AP + sg + 8] = *(const short8*)(vs + 8);
        }
        __syncthreads();

        // ---- QK^T : scores [16q x 64k] per wave, C layout ----
        f32x4 sc[4] = {};
#pragma unroll
        for (int kf = 0; kf < 4; ++kf) {
            half8 b0 = *(const half8*)&Ks[(kf * 16 + lr) * AP + g * 8];
            half8 b1 = *(const half8*)&Ks[(kf * 16 + lr) * AP + 32 + g * 8];
            sc[kf] = __builtin_amdgcn_mfma_f32_16x16x32_f16(qa0, b0, sc[kf], 0, 0, 0);
            sc[kf] = __builtin_amdgcn_mfma_f32_16x16x32_f16(qa1, b1, sc[kf], 0, 0, 0);
        }

        // ---- window mask (only edge chunks) ----
        if (c == 0) {
#pragma unroll
            for (int kf = 0; kf < 4; ++kf) {
                const int j = cs + kf * 16 + lr;
#pragma unroll
                for (int i = 0; i < 4; ++i) {
                    const int q = q0 + w * 16 + g * 4 + i;
                    if (j < q - WHALF) sc[kf][i] = -1e30f;
                }
            }
        } else if (c == 8) {
#pragma unroll
            for (int kf = 0; kf < 4; ++kf) {
                const int j = cs + kf * 16 + lr;
#pragma unroll
                for (int i = 0; i < 4; ++i) {
                    const int q = q0 + w * 16 + g * 4 + i;
                    if (j > q + WHALF) sc[kf][i] = -1e30f;
                }
            }
        }

        // ---- online softmax: row stats via 16-lane shuffle reduce ----
        float cm[4], alpha[4], rs[4];
#pragma unroll
        for (int i = 0; i < 4; ++i) {
            float v = fmaxf(fmaxf(sc[0][i], sc[1][i]), fmaxf(sc[2][i], sc[3][i]));
            v = fmaxf(v, __shfl_xor(v, 1));
            v = fmaxf(v, __shfl_xor(v, 2));
            v = fmaxf(v, __shfl_xor(v, 4));
            v = fmaxf(v, __shfl_xor(v, 8));
            cm[i] = v;
        }
#pragma unroll
        for (int i = 0; i < 4; ++i) {
            const float mn = fmaxf(fmaxf(m_[i], cm[i]), -1e4f);
            alpha[i] = __expf(m_[i] - mn);
            m_[i] = mn;
            rs[i] = 0.0f;
        }
#pragma unroll
        for (int kf = 0; kf < 4; ++kf)
#pragma unroll
            for (int i = 0; i < 4; ++i) {
                const float p = __expf(sc[kf][i] - m_[i]);
                rs[i] += p;
                *(_Float16*)&Ps[(w * 16 + g * 4 + i) * AP + kf * 16 + lr] = (_Float16)p;
            }
#pragma unroll
        for (int i = 0; i < 4; ++i) {
            float v = rs[i];
            v += __shfl_xor(v, 1);
            v += __shfl_xor(v, 2);
            v += __shfl_xor(v, 4);
            v += __shfl_xor(v, 8);
            l_[i] = l_[i] * alpha[i] + v;
        }
#pragma unroll
        for (int df = 0; df < 4; ++df)
#pragma unroll
            for (int i = 0; i < 4; ++i) o[df][i] *= alpha[i];

        // ---- P @ V ----
        half8 pa0 = *(const half8*)&Ps[(w * 16 + lr) * AP + g * 8];
        half8 pa1 = *(const half8*)&Ps[(w * 16 + lr) * AP + 32 + g * 8];
#pragma unroll
        for (int df = 0; df < 4; ++df) {
            half8 vb0 = *(const half8*)&Vs[(df * 16 + lr) * AP + g * 8];
            half8 vb1 = *(const half8*)&Vs[(df * 16 + lr) * AP + 32 + g * 8];
            o[df] = __builtin_amdgcn_mfma_f32_16x16x32_f16(pa0, vb0, o[df], 0, 0, 0);
            o[df] = __builtin_amdgcn_mfma_f32_16x16x32_f16(pa1, vb1, o[df], 0, 0, 0);
        }
        __syncthreads();
    }

    // ---- epilogue: normalize, store fp16 ----
    float inv[4];
#pragma unroll
    for (int i = 0; i < 4; ++i) inv[i] = 1.0f / l_[i];
#pragma unroll
    for (int df = 0; df < 4; ++df)
#pragma unroll
        for (int i = 0; i < 4; ++i) {
            const float v = o[df][i] * inv[i];
            const size_t off = (rowbase + q0 + w * 16 + g * 4 + i) * 1024
                             + h * HDIM + df * 16 + lr;
            *(_Float16*)&Oa[off] = (_Float16)v;
        }
}

// ---------------------------------------------------------------------------
// fp32 fallback GEMM + attention (only if ws too small)
// ---------------------------------------------------------------------------
#define BM 64
#define BN 64
#define BK 16

__global__ __launch_bounds__(256)
void gemm_bias_kernel(const float* __restrict__ A, const float* __restrict__ W,
                      const float* __restrict__ bias, float* __restrict__ C,
                      int M, int N, int K)
{
    __shared__ float As[BK][BM + 4];
    __shared__ float Bs[BK][BN + 4];
    const int tid = threadIdx.x;
    const int tx = tid & 15, ty = tid >> 4;
    const int row0 = blockIdx.y * BM;
    const int col0 = blockIdx.x * BN;
    float acc[4][4] = {};
    const int ar = tid >> 2;
    const int ak = (tid & 3) * 4;
    const int br = tid >> 4;
    const int bc = (tid & 15) * 4;
    for (int k0 = 0; k0 < K; k0 += BK) {
        float4 a = *(const float4*)&A[(size_t)(row0 + ar) * K + k0 + ak];
        float4 b = *(const float4*)&W[(size_t)(k0 + br) * N + col0 + bc];
        As[ak + 0][ar] = a.x; As[ak + 1][ar] = a.y;
        As[ak + 2][ar] = a.z; As[ak + 3][ar] = a.w;
        *(float4*)&Bs[br][bc] = b;
        __syncthreads();
#pragma unroll
        for (int kk = 0; kk < BK; ++kk) {
            float4 av = *(const float4*)&As[kk][ty * 4];
            float4 bv = *(const float4*)&Bs[kk][tx * 4];
            float aa[4] = {av.x, av.y, av.z, av.w};
            float bb[4] = {bv.x, bv.y, bv.z, bv.w};
#pragma unroll
            for (int i = 0; i < 4; ++i)
#pragma unroll
                for (int j = 0; j < 4; ++j)
                    acc[i][j] = fmaf(aa[i], bb[j], acc[i][j]);
        }
        __syncthreads();
    }
    const float4 bvec = *(const float4*)&bias[col0 + tx * 4];
    const float bb[4] = {bvec.x, bvec.y, bvec.z, bvec.w};
#pragma unroll
    for (int i = 0; i < 4; ++i) {
        float4 oo;
        oo.x = acc[i][0] + bb[0]; oo.y = acc[i][1] + bb[1];
        oo.z = acc[i][2] + bb[2]; oo.w = acc[i][3] + bb[3];
        *(float4*)&C[(size_t)(row0 + ty * 4 + i) * N + col0 + tx * 4] = oo;
    }
}

#define QT 32
#define KT 64

__global__ __launch_bounds__(256)
void attn_kernel(const float* __restrict__ Qm, int ldq,
                 const float* __restrict__ Km, int ldk,
                 const float* __restrict__ Vm, int ldv,
                 float* __restrict__ Om, int ldo)
{
    __shared__ float Qs[QT][HDIM + 4];
    __shared__ float KVs[KT][HDIM + 4];
    __shared__ float Ps[QT][KT + 1];
    __shared__ float red[8][QT];
    __shared__ float m_s[QT], l_s[QT], alpha_s[QT];
    const int tid = threadIdx.x;
    const int b  = blockIdx.y / NHEADS;
    const int h  = blockIdx.y % NHEADS;
    const int q0 = blockIdx.x * QT;
    const int r  = tid & 31;
    const int cg = tid >> 5;
    const int d0 = cg * 8;
    {
        const int qr = tid >> 3;
        const int qd = (tid & 7) * 8;
        const float* src = Qm + (size_t)(b * SEQ + q0 + qr) * ldq + h * HDIM + qd;
        *(float4*)&Qs[qr][qd]     = *(const float4*)(src);
        *(float4*)&Qs[qr][qd + 4] = *(const float4*)(src + 4);
    }
    if (tid < QT) { m_s[tid] = -1e30f; l_s[tid] = 0.0f; }
    __syncthreads();
    float qreg[HDIM];
#pragma unroll
    for (int d4 = 0; d4 < HDIM; d4 += 4) {
        float4 t = *(const float4*)&Qs[r][d4];
        qreg[d4] = t.x; qreg[d4 + 1] = t.y; qreg[d4 + 2] = t.z; qreg[d4 + 3] = t.w;
    }
    float o[8] = {};
    const int iq = q0 + r;
    int lo = q0 - WHALF; if (lo < 0) lo = 0;
    const int cs0 = lo & ~(KT - 1);
    int hi = q0 + QT + WHALF; if (hi > SEQ) hi = SEQ;
    const int nch = (hi - cs0 + KT - 1) / KT;
    const int kr0 = tid >> 4;
    const int kc  = (tid & 15) * 4;
    for (int ch = 0; ch < nch; ++ch) {
        const int cs = cs0 + ch * KT;
#pragma unroll
        for (int r4 = 0; r4 < 4; ++r4) {
            const int row = kr0 + r4 * 16;
            const int j = cs + row;
            float4 v = make_float4(0.f, 0.f, 0.f, 0.f);
            if (j < SEQ)
                v = *(const float4*)&Km[(size_t)(b * SEQ + j) * ldk + h * HDIM + kc];
            *(float4*)&KVs[row][kc] = v;
        }
        __syncthreads();
        float s[8];
#pragma unroll
        for (int cc = 0; cc < 8; ++cc) {
            const int cidx = d0 + cc;
            float acc = 0.0f;
#pragma unroll
            for (int d4 = 0; d4 < HDIM; d4 += 4) {
                float4 kv = *(const float4*)&KVs[cidx][d4];
                acc = fmaf(qreg[d4],     kv.x, acc);
                acc = fmaf(qreg[d4 + 1], kv.y, acc);
                acc = fmaf(qreg[d4 + 2], kv.z, acc);
                acc = fmaf(qreg[d4 + 3], kv.w, acc);
            }
            const int j = cs + cidx;
            const bool valid = (j < SEQ) && (j >= iq - WHALF) && (j <= iq + WHALF);
            s[cc] = valid ? acc * 0.125f : -1e30f;
        }
        float lm = s[0];
#pragma unroll
        for (int cc = 1; cc < 8; ++cc) lm = fmaxf(lm, s[cc]);
        red[cg][r] = lm;
        __syncthreads();
        if (tid < QT) {
            float m = m_s[tid];
            float mc = red[0][tid];
#pragma unroll
            for (int g2 = 1; g2 < 8; ++g2) mc = fmaxf(mc, red[g2][tid]);
            const float mn = fmaxf(m, mc);
            alpha_s[tid] = __expf(m - mn);
            m_s[tid] = mn;
        }
        __syncthreads();
        const float mn = m_s[r];
        float ls = 0.0f;
#pragma unroll
        for (int cc = 0; cc < 8; ++cc) {
            const float p = __expf(s[cc] - mn);
            Ps[r][d0 + cc] = p;
            ls += p;
        }
        red[cg][r] = ls;
        __syncthreads();
        if (tid < QT) {
            float sum = red[0][tid];
#pragma unroll
            for (int g2 = 1; g2 < 8; ++g2) sum += red[g2][tid];
            l_s[tid] = l_s[tid] * alpha_s[tid] + sum;
        }
#pragma unroll
        for (int r4 = 0; r4 < 4; ++r4) {
            const int row = kr0 + r4 * 16;
            const int j = cs + row;
            float4 v = make_float4(0.f, 0.f, 0.f, 0.f);
            if (j < SEQ)
                v = *(const float4*)&Vm[(size_t)(b * SEQ + j) * ldv + h * HDIM + kc];
            *(float4*)&KVs[row][kc] = v;
        }
        {
            const float al = alpha_s[r];
#pragma unroll
            for (int dd = 0; dd < 8; ++dd) o[dd] *= al;
        }
        __syncthreads();
        for (int j = 0; j < KT; ++j) {
            const float p = Ps[r][j];
            float4 v0 = *(const float4*)&KVs[j][d0];
            float4 v1 = *(const float4*)&KVs[j][d0 + 4];
            o[0] = fmaf(p, v0.x, o[0]); o[1] = fmaf(p, v0.y, o[1]);
            o[2] = fmaf(p, v0.z, o[2]); o[3] = fmaf(p, v0.w, o[3]);
            o[4] = fmaf(p, v1.x, o[4]); o[5] = fmaf(p, v1.y, o[5]);
            o[6] = fmaf(p, v1.z, o[6]); o[7] = fmaf(p, v1.w, o[7]);
        }
        __syncthreads();
    }
    const float inv = 1.0f / l_s[r];
    float4 o0, o1;
    o0.x = o[0] * inv; o0.y = o[1] * inv; o0.z = o[2] * inv; o0.w = o[3] * inv;
    o1.x = o[4] * inv; o1.y = o[5] * inv; o1.z = o[6] * inv; o1.w = o[7] * inv;
    float* dst = Om + (size_t)(b * SEQ + q0 + r) * ldo + h * HDIM + d0;
    *(float4*)dst       = o0;
    *(float4*)(dst + 4) = o1;
}

// ---------------------------------------------------------------------------
extern "C" void kernel_launch(void* const* d_in, const int* in_sizes, int n_in,
                              void* d_out, int out_size, void* d_ws, size_t ws_size,
                              hipStream_t stream)
{
    const float* x  = (const float*)d_in[0];
    const float* Wq = (const float*)d_in[1];
    const float* bq = (const float*)d_in[2];
    const float* Wk = (const float*)d_in[3];
    const float* bk = (const float*)d_in[4];
    const float* Wv = (const float*)d_in[5];
    const float* bv = (const float*)d_in[6];
    const float* Wo = (const float*)d_in[7];
    const float* bo = (const float*)d_in[8];
    float* out = (float*)d_out;

    const int M = BATCH * SEQ;                 // 4096
    const size_t MK = (size_t)M * EMB;         // 4M elements

    const size_t need = ((size_t)40 << 20) + 16384;
    dim3 blk(256);

    if (ws_size >= need) {
        // ws layout (fp16):
        //  [0,8M)    Wcat^T  [4096][1024]  (Wq/8 | Wk | Wv | Wo)
        //  [8M,16M)  xh -> attn-out (reused)
        //  [16M,32M) QKb [4096][2048]  (Q/8 | K)
        //  [32M,40M) Vt  [2048][2048]  (V^T per b: rows h*64+d)
        //  [40M,+12K) bias_cat fp32
        unsigned short* Wh  = (unsigned short*)d_ws;
        unsigned short* xh  = Wh + (size_t)4096 * EMB;
        unsigned short* QKb = xh + MK;
        unsigned short* Vt  = QKb + (size_t)4096 * 2048;
        unsigned short* Oa  = xh;    // reuse after QKV GEMM consumed x
        float* bias_cat = (float*)((char*)d_ws + ((size_t)40 << 20));

        hipLaunchKernelGGL(cast16_kernel, dim3((int)(MK / (256 * 8))), blk, 0, stream,
                           x, xh, (int)MK);
        hipLaunchKernelGGL(wsplit16_t_kernel, dim3(32, 32, 4), blk, 0, stream,
                           Wq, Wk, Wv, Wo, Wh);
        hipLaunchKernelGGL(bias_cat_kernel, dim3(12), blk, 0, stream, bq, bk, bv, bias_cat);

        // fused QKV GEMM: Q,K -> QKb fp16; V -> Vt fp16 transposed
        hipLaunchKernelGGL((gemm_f16_kernel<1>), dim3(24, 32), blk, 0, stream,
                           xh, Wh, bias_cat, (void*)QKb, (void*)Vt, 0, EMB);

        // fp16 MFMA flash attention
        hipLaunchKernelGGL(attn_f16_kernel, dim3(1024), blk, 0, stream, QKb, Vt, Oa);

        // final GEMM: attn @ Wo + bo -> fp32 out
        hipLaunchKernelGGL((gemm_f16_kernel<0>), dim3(8, 32), blk, 0, stream,
                           Oa, Wh + (size_t)3072 * EMB, bo, (void*)out, nullptr, EMB, EMB);
    } else {
        float* Qb = (float*)d_ws;
        float* Kb = Qb + MK;
        float* Vb = out;
        dim3 ggrid(EMB / BN, M / BM);
        hipLaunchKernelGGL(gemm_bias_kernel, ggrid, blk, 0, stream, x, Wq, bq, Qb, M, EMB, EMB);
        hipLaunchKernelGGL(gemm_bias_kernel, ggrid, blk, 0, stream, x, Wk, bk, Kb, M, EMB, EMB);
        hipLaunchKernelGGL(gemm_bias_kernel, ggrid, blk, 0, stream, x, Wv, bv, Vb, M, EMB, EMB);
        hipLaunchKernelGGL(attn_kernel, dim3(SEQ / QT, BATCH * NHEADS), blk, 0, stream,
                           Qb, EMB, Kb, EMB, Vb, EMB, Qb, EMB);
        hipLaunchKernelGGL(gemm_bias_kernel, ggrid, blk, 0, stream, Qb, Wo, bo, out, M, EMB, EMB);
    }
}

// Round 5
// 208.203 us; speedup vs baseline: 3.5417x; 1.0019x over previous
//
#include <hip/hip_runtime.h>
#include <math.h>
#include <stdint.h>

#define BATCH 2
#define SEQ   2048
#define EMB   1024
#define NHEADS 16
#define HDIM  64
#define WHALF 256      // WINDOW_SIZE/2

typedef __attribute__((ext_vector_type(8))) short short8;
typedef __attribute__((ext_vector_type(8))) _Float16 half8;
typedef __attribute__((ext_vector_type(4))) _Float16 half4;
typedef __attribute__((ext_vector_type(4))) float f32x4;

// ---------------------------------------------------------------------------
// cast fp32 -> fp16 (8 per thread)
// ---------------------------------------------------------------------------
__global__ __launch_bounds__(256)
void cast16_kernel(const float* __restrict__ in, unsigned short* __restrict__ o16, int n)
{
    const int i = (blockIdx.x * 256 + threadIdx.x) * 8;
    if (i >= n) return;
    float4 v0 = *(const float4*)&in[i];
    float4 v1 = *(const float4*)&in[i + 4];
    half8 h;
    h[0] = (_Float16)v0.x; h[1] = (_Float16)v0.y;
    h[2] = (_Float16)v0.z; h[3] = (_Float16)v0.w;
    h[4] = (_Float16)v1.x; h[5] = (_Float16)v1.y;
    h[6] = (_Float16)v1.z; h[7] = (_Float16)v1.w;
    *(half8*)&o16[i] = h;
}

// ---------------------------------------------------------------------------
// transpose + cast the four 1024x1024 weights into one cat [4096][1024] fp16
// buffer (Wq^T/8 | Wk^T | Wv^T | Wo^T).
// ---------------------------------------------------------------------------
__global__ __launch_bounds__(256)
void wsplit16_t_kernel(const float* __restrict__ W0, const float* __restrict__ W1,
                       const float* __restrict__ W2, const float* __restrict__ W3,
                       unsigned short* __restrict__ o16)
{
    __shared__ float t[32][33];
    const float* W = (blockIdx.z == 0) ? W0 : (blockIdx.z == 1) ? W1
                   : (blockIdx.z == 2) ? W2 : W3;
    const float scale = (blockIdx.z == 0) ? 0.125f : 1.0f;
    const int n0 = blockIdx.x * 32;
    const int k0 = blockIdx.y * 32;
    const int tx = threadIdx.x & 31, ty = threadIdx.x >> 5;
#pragma unroll
    for (int i = 0; i < 4; ++i)
        t[ty + i * 8][tx] = W[(size_t)(k0 + ty + i * 8) * EMB + n0 + tx];
    __syncthreads();
#pragma unroll
    for (int i = 0; i < 4; ++i) {
        float v = t[tx][ty + i * 8] * scale;
        size_t o = (size_t)(blockIdx.z * EMB + n0 + ty + i * 8) * EMB + k0 + tx;
        *(_Float16*)&o16[o] = (_Float16)v;
    }
}

__global__ __launch_bounds__(256)
void bias_cat_kernel(const float* __restrict__ bq, const float* __restrict__ bk,
                     const float* __restrict__ bv, float* __restrict__ out)
{
    const int i = blockIdx.x * 256 + threadIdx.x;
    if (i < 1024)      out[i] = bq[i] * 0.125f;
    else if (i < 2048) out[i] = bk[i - 1024];
    else if (i < 3072) out[i] = bv[i - 2048];
}

#define GLDS(gp, lp) __builtin_amdgcn_global_load_lds(                       \
    (const __attribute__((address_space(1))) void*)(gp),                     \
    (__attribute__((address_space(3))) void*)(lp), 16, 0, 0)

// ---------------------------------------------------------------------------
// QKV fp16 MFMA GEMM: C = A @ B^T + bias.  A:[4096][1024] fp16, B:[3072][1024].
// 128x128 tile, BK=32. Epilogue staged through LDS for coalesced writes:
//   cols < 2048 -> QK fp16 [4096][2048] row-major
//   cols >= 2048 -> Vt fp16 transposed: Vt[b*1024 + (col-2048)][s]
// ---------------------------------------------------------------------------
#define TRS 136   // tr row stride in halves (272 B: 16B-aligned)

__global__ __launch_bounds__(256)
void gemm_f16_qkv_kernel(const unsigned short* __restrict__ A,
                         const unsigned short* __restrict__ B,
                         const float* __restrict__ bias,
                         _Float16* __restrict__ QK,
                         _Float16* __restrict__ Vt, int K)
{
    __shared__ unsigned short sA[128 * 32], sB[128 * 32];
    __shared__ _Float16 tr[128 * TRS];    // epilogue staging (34 KB)

    const int tid = threadIdx.x;
    const int l = tid & 63;
    const int w = tid >> 6;
    const int wm = w >> 1, wn = w & 1;
    const int row0 = blockIdx.y * 128;
    const int col0 = blockIdx.x * 128;

    f32x4 acc[4][4] = {};

    const int sr = tid >> 2;
    const int sk = (tid & 3) * 8;
    const unsigned short* pA = A + (size_t)(row0 + sr) * K + sk;
    const unsigned short* pB = B + (size_t)(col0 + sr) * K + sk;
    const size_t rstep = (size_t)64 * K;

    const int kq = (l >> 4) * 8;
    const int lr = l & 15;
    const int lq = l >> 4;

    for (int k0 = 0; k0 < K; k0 += 32) {
        GLDS(pA + k0,         &sA[tid * 8]);
        GLDS(pA + rstep + k0, &sA[2048 + tid * 8]);
        GLDS(pB + k0,         &sB[tid * 8]);
        GLDS(pB + rstep + k0, &sB[2048 + tid * 8]);
        __syncthreads();

        half8 af[4], bf[4];
#pragma unroll
        for (int f = 0; f < 4; ++f) {
            af[f] = *(const half8*)&sA[(wm * 64 + f * 16 + lr) * 32 + kq];
            bf[f] = *(const half8*)&sB[(wn * 64 + f * 16 + lr) * 32 + kq];
        }
#pragma unroll
        for (int mf = 0; mf < 4; ++mf)
#pragma unroll
            for (int nf = 0; nf < 4; ++nf)
                acc[mf][nf] = __builtin_amdgcn_mfma_f32_16x16x32_f16(af[mf], bf[nf], acc[mf][nf], 0, 0, 0);
        __syncthreads();
    }

    // ---- epilogue via LDS (coalesced global writes) ----
    if (col0 < 2048) {
        // QK: tr[r_local][c]
#pragma unroll
        for (int nf = 0; nf < 4; ++nf) {
            const int c = wn * 64 + nf * 16 + lr;
            const float bv = bias[col0 + c];
#pragma unroll
            for (int mf = 0; mf < 4; ++mf) {
                const int rl = wm * 64 + mf * 16 + lq * 4;
#pragma unroll
                for (int i = 0; i < 4; ++i)
                    tr[(rl + i) * TRS + c] = (_Float16)(acc[mf][nf][i] + bv);
            }
        }
        __syncthreads();
        const int r = tid >> 1, seg = (tid & 1) * 64;
        _Float16* dst = QK + (size_t)(row0 + r) * 2048 + col0 + seg;
#pragma unroll
        for (int t = 0; t < 8; ++t)
            *(half8*)&dst[t * 8] = *(const half8*)&tr[r * TRS + seg + t * 8];
    } else {
        // V: tr[c][r_local]  (transpose in LDS)
#pragma unroll
        for (int nf = 0; nf < 4; ++nf) {
            const int c = wn * 64 + nf * 16 + lr;
            const float bv = bias[col0 + c];
#pragma unroll
            for (int mf = 0; mf < 4; ++mf) {
                const int rl = wm * 64 + mf * 16 + lq * 4;
#pragma unroll
                for (int i = 0; i < 4; ++i)
                    tr[c * TRS + rl + i] = (_Float16)(acc[mf][nf][i] + bv);
            }
        }
        __syncthreads();
        const int c = tid >> 1, seg = (tid & 1) * 64;
        const int vb = row0 >> 11;             // batch index
        const int s0 = (row0 & 2047) + seg;
        _Float16* dst = Vt + ((size_t)(vb * 1024 + (col0 - 2048) + c)) * 2048 + s0;
#pragma unroll
        for (int t = 0; t < 8; ++t)
            *(half8*)&dst[t * 8] = *(const half8*)&tr[c * TRS + seg + t * 8];
    }
}

// ---------------------------------------------------------------------------
// final fp16 MFMA GEMM, 64x128 tile (2 blocks/CU): C fp32 = A @ B^T + bias
// ---------------------------------------------------------------------------
__global__ __launch_bounds__(256)
void gemm_f16_m64_kernel(const unsigned short* __restrict__ A,
                         const unsigned short* __restrict__ B,
                         const float* __restrict__ bias,
                         float* __restrict__ C, int ldc, int K)
{
    __shared__ unsigned short sA[64 * 32], sB[128 * 32];

    const int tid = threadIdx.x;
    const int l = tid & 63;
    const int w = tid >> 6;
    const int wm = w >> 1, wn = w & 1;
    const int row0 = blockIdx.y * 64;
    const int col0 = blockIdx.x * 128;

    f32x4 acc[2][4] = {};

    const int sr = tid >> 2;
    const int sk = (tid & 3) * 8;
    const unsigned short* pA = A + (size_t)(row0 + sr) * K + sk;
    const unsigned short* pB = B + (size_t)(col0 + sr) * K + sk;
    const size_t rstep = (size_t)64 * K;

    const int kq = (l >> 4) * 8;
    const int lr = l & 15;
    const int lq = l >> 4;

    for (int k0 = 0; k0 < K; k0 += 32) {
        GLDS(pA + k0,         &sA[tid * 8]);
        GLDS(pB + k0,         &sB[tid * 8]);
        GLDS(pB + rstep + k0, &sB[2048 + tid * 8]);
        __syncthreads();

        half8 af[2], bf[4];
#pragma unroll
        for (int f = 0; f < 2; ++f)
            af[f] = *(const half8*)&sA[(wm * 32 + f * 16 + lr) * 32 + kq];
#pragma unroll
        for (int f = 0; f < 4; ++f)
            bf[f] = *(const half8*)&sB[(wn * 64 + f * 16 + lr) * 32 + kq];
#pragma unroll
        for (int mf = 0; mf < 2; ++mf)
#pragma unroll
            for (int nf = 0; nf < 4; ++nf)
                acc[mf][nf] = __builtin_amdgcn_mfma_f32_16x16x32_f16(af[mf], bf[nf], acc[mf][nf], 0, 0, 0);
        __syncthreads();
    }

#pragma unroll
    for (int nf = 0; nf < 4; ++nf) {
        const int c = wn * 64 + nf * 16 + lr;
        const float bv = bias[col0 + c];
#pragma unroll
        for (int mf = 0; mf < 2; ++mf) {
            const int r = row0 + wm * 32 + mf * 16 + lq * 4;
#pragma unroll
            for (int i = 0; i < 4; ++i)
                C[(size_t)(r + i) * ldc + col0 + c] = acc[mf][nf][i] + bv;
        }
    }
}

// ---------------------------------------------------------------------------
// fp16 MFMA sliding-window flash attention, S^T softmax orientation.
// QKb: [B*S][2048] fp16 (Q/8 | K).  Vt: [(b*1024+h*64+d)][2048] fp16.
// 256 thr = 4 waves; 64-q tile; 64-key chunks. Scores computed as
// S^T = mfma(K_frag, Q_frag): row=key, col=q -> each lane owns ONE q row;
// softmax reductions = 2 shuffles; P stored as 4 vectorized writes.
// Output: fp16 [B*S][1024]. Grid 1024, gid&7 = XCD slot.
// ---------------------------------------------------------------------------
#define AP 66   // padded LDS row stride (halves)

__global__ __launch_bounds__(256)
void attn_f16_kernel(const unsigned short* __restrict__ QKb,
                     const unsigned short* __restrict__ Vt,
                     unsigned short* __restrict__ Oa)
{
    __shared__ unsigned short Qs[64 * AP], Ks[64 * AP], Vs[64 * AP], Ps[64 * AP];

    const int tid = threadIdx.x;
    const int gid = blockIdx.x;
    const int X = gid & 7, rest = gid >> 3;
    const int hg = rest & 3, tile = rest >> 2;
    const int bh = X * 4 + hg;
    const int b = bh >> 4, h = bh & 15;
    const int q0 = tile * 64;

    const int l = tid & 63, w = tid >> 6;
    const int lr = l & 15, g = l >> 4;

    const size_t rowbase = (size_t)b * SEQ;

    // stage Q tile
    {
        const int r = tid >> 2, sg = (tid & 3) * 16;
        const unsigned short* src = QKb + (rowbase + q0 + r) * 2048 + h * HDIM + sg;
        *(short8*)&Qs[r * AP + sg]     = *(const short8*)src;
        *(short8*)&Qs[r * AP + sg + 8] = *(const short8*)(src + 8);
    }
    __syncthreads();

    half8 qa0 = *(const half8*)&Qs[(w * 16 + lr) * AP + g * 8];
    half8 qa1 = *(const half8*)&Qs[(w * 16 + lr) * AP + 32 + g * 8];

    f32x4 o[4] = {};
    float m_ = -1e30f, l_ = 0.0f;            // state for q = q0 + w*16 + lr
    const int q = q0 + w * 16 + lr;

    const int c_begin = (q0 >= WHALF) ? 0 : (WHALF - q0) >> 6;
    int c_end = (SEQ + 192 - q0) >> 6; if (c_end > 8) c_end = 8;

    for (int c = c_begin; c <= c_end; ++c) {
        const int cs = q0 - WHALF + c * 64;

        // stage K chunk + V^T chunk (vectorized)
        {
            const int r = tid >> 2, sg = (tid & 3) * 16;
            const unsigned short* ks = QKb + (rowbase + cs + r) * 2048 + 1024 + h * HDIM + sg;
            *(short8*)&Ks[r * AP + sg]     = *(const short8*)ks;
            *(short8*)&Ks[r * AP + sg + 8] = *(const short8*)(ks + 8);
            const unsigned short* vs = Vt + ((size_t)(b * 1024 + h * HDIM + r)) * 2048 + cs + sg;
            *(short8*)&Vs[r * AP + sg]     = *(const short8*)vs;
            *(short8*)&Vs[r * AP + sg + 8] = *(const short8*)(vs + 8);
        }
        __syncthreads();

        // ---- S^T = K Q^T : row=key (g*4+i within kf group), col=q (lr) ----
        f32x4 sc[4] = {};
#pragma unroll
        for (int kf = 0; kf < 4; ++kf) {
            half8 a0 = *(const half8*)&Ks[(kf * 16 + lr) * AP + g * 8];
            half8 a1 = *(const half8*)&Ks[(kf * 16 + lr) * AP + 32 + g * 8];
            sc[kf] = __builtin_amdgcn_mfma_f32_16x16x32_f16(a0, qa0, sc[kf], 0, 0, 0);
            sc[kf] = __builtin_amdgcn_mfma_f32_16x16x32_f16(a1, qa1, sc[kf], 0, 0, 0);
        }

        // ---- window mask (edge chunks only) ----
        if (c == 0) {
#pragma unroll
            for (int kf = 0; kf < 4; ++kf)
#pragma unroll
                for (int i = 0; i < 4; ++i) {
                    const int key = cs + kf * 16 + g * 4 + i;
                    if (key < q - WHALF) sc[kf][i] = -1e30f;
                }
        } else if (c == 8) {
#pragma unroll
            for (int kf = 0; kf < 4; ++kf)
#pragma unroll
                for (int i = 0; i < 4; ++i) {
                    const int key = cs + kf * 16 + g * 4 + i;
                    if (key > q + WHALF) sc[kf][i] = -1e30f;
                }
        }

        // ---- online softmax: all 16 values belong to q=lr -> 2-step reduce ----
        float cm = sc[0][0];
#pragma unroll
        for (int kf = 0; kf < 4; ++kf)
#pragma unroll
            for (int i = 0; i < 4; ++i) cm = fmaxf(cm, sc[kf][i]);
        cm = fmaxf(cm, __shfl_xor(cm, 16));
        cm = fmaxf(cm, __shfl_xor(cm, 32));

        const float mn = fmaxf(fmaxf(m_, cm), -1e4f);
        const float alpha = __expf(m_ - mn);
        m_ = mn;

        float rs = 0.0f;
#pragma unroll
        for (int kf = 0; kf < 4; ++kf) {
            half4 pk;
#pragma unroll
            for (int i = 0; i < 4; ++i) {
                const float p = __expf(sc[kf][i] - mn);
                rs += p;
                pk[i] = (_Float16)p;
            }
            *(half4*)&Ps[(w * 16 + lr) * AP + kf * 16 + g * 4] = pk;
        }
        rs += __shfl_xor(rs, 16);
        rs += __shfl_xor(rs, 32);
        l_ = l_ * alpha + rs;

        // broadcast alpha to this lane's accumulator rows (q = g*4+i)
        float al[4];
#pragma unroll
        for (int i = 0; i < 4; ++i)
            al[i] = __shfl(alpha, (l & 48) | (g * 4 + i));
#pragma unroll
        for (int df = 0; df < 4; ++df)
#pragma unroll
            for (int i = 0; i < 4; ++i) o[df][i] *= al[i];

        // ---- P @ V ----
        half8 pa0 = *(const half8*)&Ps[(w * 16 + lr) * AP + g * 8];
        half8 pa1 = *(const half8*)&Ps[(w * 16 + lr) * AP + 32 + g * 8];
#pragma unroll
        for (int df = 0; df < 4; ++df) {
            half8 vb0 = *(const half8*)&Vs[(df * 16 + lr) * AP + g * 8];
            half8 vb1 = *(const half8*)&Vs[(df * 16 + lr) * AP + 32 + g * 8];
            o[df] = __builtin_amdgcn_mfma_f32_16x16x32_f16(pa0, vb0, o[df], 0, 0, 0);
            o[df] = __builtin_amdgcn_mfma_f32_16x16x32_f16(pa1, vb1, o[df], 0, 0, 0);
        }
        __syncthreads();
    }

    // ---- epilogue: per-row 1/l broadcast, store fp16 ----
    float invl[4];
#pragma unroll
    for (int i = 0; i < 4; ++i)
        invl[i] = 1.0f / __shfl(l_, (l & 48) | (g * 4 + i));
#pragma unroll
    for (int df = 0; df < 4; ++df)
#pragma unroll
        for (int i = 0; i < 4; ++i) {
            const float v = o[df][i] * invl[i];
            const size_t off = (rowbase + q0 + w * 16 + g * 4 + i) * 1024
                             + h * HDIM + df * 16 + lr;
            *(_Float16*)&Oa[off] = (_Float16)v;
        }
}

// ---------------------------------------------------------------------------
// fp32 fallback GEMM + attention (only if ws too small)
// ---------------------------------------------------------------------------
#define BM 64
#define BN 64
#define BK 16

__global__ __launch_bounds__(256)
void gemm_bias_kernel(const float* __restrict__ A, const float* __restrict__ W,
                      const float* __restrict__ bias, float* __restrict__ C,
                      int M, int N, int K)
{
    __shared__ float As[BK][BM + 4];
    __shared__ float Bs[BK][BN + 4];
    const int tid = threadIdx.x;
    const int tx = tid & 15, ty = tid >> 4;
    const int row0 = blockIdx.y * BM;
    const int col0 = blockIdx.x * BN;
    float acc[4][4] = {};
    const int ar = tid >> 2;
    const int ak = (tid & 3) * 4;
    const int br = tid >> 4;
    const int bc = (tid & 15) * 4;
    for (int k0 = 0; k0 < K; k0 += BK) {
        float4 a = *(const float4*)&A[(size_t)(row0 + ar) * K + k0 + ak];
        float4 b = *(const float4*)&W[(size_t)(k0 + br) * N + col0 + bc];
        As[ak + 0][ar] = a.x; As[ak + 1][ar] = a.y;
        As[ak + 2][ar] = a.z; As[ak + 3][ar] = a.w;
        *(float4*)&Bs[br][bc] = b;
        __syncthreads();
#pragma unroll
        for (int kk = 0; kk < BK; ++kk) {
            float4 av = *(const float4*)&As[kk][ty * 4];
            float4 bv = *(const float4*)&Bs[kk][tx * 4];
            float aa[4] = {av.x, av.y, av.z, av.w};
            float bb[4] = {bv.x, bv.y, bv.z, bv.w};
#pragma unroll
            for (int i = 0; i < 4; ++i)
#pragma unroll
                for (int j = 0; j < 4; ++j)
                    acc[i][j] = fmaf(aa[i], bb[j], acc[i][j]);
        }
        __syncthreads();
    }
    const float4 bvec = *(const float4*)&bias[col0 + tx * 4];
    const float bb[4] = {bvec.x, bvec.y, bvec.z, bvec.w};
#pragma unroll
    for (int i = 0; i < 4; ++i) {
        float4 oo;
        oo.x = acc[i][0] + bb[0]; oo.y = acc[i][1] + bb[1];
        oo.z = acc[i][2] + bb[2]; oo.w = acc[i][3] + bb[3];
        *(float4*)&C[(size_t)(row0 + ty * 4 + i) * N + col0 + tx * 4] = oo;
    }
}

#define QT 32
#define KT 64

__global__ __launch_bounds__(256)
void attn_kernel(const float* __restrict__ Qm, int ldq,
                 const float* __restrict__ Km, int ldk,
                 const float* __restrict__ Vm, int ldv,
                 float* __restrict__ Om, int ldo)
{
    __shared__ float Qs[QT][HDIM + 4];
    __shared__ float KVs[KT][HDIM + 4];
    __shared__ float Ps[QT][KT + 1];
    __shared__ float red[8][QT];
    __shared__ float m_s[QT], l_s[QT], alpha_s[QT];
    const int tid = threadIdx.x;
    const int b  = blockIdx.y / NHEADS;
    const int h  = blockIdx.y % NHEADS;
    const int q0 = blockIdx.x * QT;
    const int r  = tid & 31;
    const int cg = tid >> 5;
    const int d0 = cg * 8;
    {
        const int qr = tid >> 3;
        const int qd = (tid & 7) * 8;
        const float* src = Qm + (size_t)(b * SEQ + q0 + qr) * ldq + h * HDIM + qd;
        *(float4*)&Qs[qr][qd]     = *(const float4*)(src);
        *(float4*)&Qs[qr][qd + 4] = *(const float4*)(src + 4);
    }
    if (tid < QT) { m_s[tid] = -1e30f; l_s[tid] = 0.0f; }
    __syncthreads();
    float qreg[HDIM];
#pragma unroll
    for (int d4 = 0; d4 < HDIM; d4 += 4) {
        float4 t = *(const float4*)&Qs[r][d4];
        qreg[d4] = t.x; qreg[d4 + 1] = t.y; qreg[d4 + 2] = t.z; qreg[d4 + 3] = t.w;
    }
    float o[8] = {};
    const int iq = q0 + r;
    int lo = q0 - WHALF; if (lo < 0) lo = 0;
    const int cs0 = lo & ~(KT - 1);
    int hi = q0 + QT + WHALF; if (hi > SEQ) hi = SEQ;
    const int nch = (hi - cs0 + KT - 1) / KT;
    const int kr0 = tid >> 4;
    const int kc  = (tid & 15) * 4;
    for (int ch = 0; ch < nch; ++ch) {
        const int cs = cs0 + ch * KT;
#pragma unroll
        for (int r4 = 0; r4 < 4; ++r4) {
            const int row = kr0 + r4 * 16;
            const int j = cs + row;
            float4 v = make_float4(0.f, 0.f, 0.f, 0.f);
            if (j < SEQ)
                v = *(const float4*)&Km[(size_t)(b * SEQ + j) * ldk + h * HDIM + kc];
            *(float4*)&KVs[row][kc] = v;
        }
        __syncthreads();
        float s[8];
#pragma unroll
        for (int cc = 0; cc < 8; ++cc) {
            const int cidx = d0 + cc;
            float acc = 0.0f;
#pragma unroll
            for (int d4 = 0; d4 < HDIM; d4 += 4) {
                float4 kv = *(const float4*)&KVs[cidx][d4];
                acc = fmaf(qreg[d4],     kv.x, acc);
                acc = fmaf(qreg[d4 + 1], kv.y, acc);
                acc = fmaf(qreg[d4 + 2], kv.z, acc);
                acc = fmaf(qreg[d4 + 3], kv.w, acc);
            }
            const int j = cs + cidx;
            const bool valid = (j < SEQ) && (j >= iq - WHALF) && (j <= iq + WHALF);
            s[cc] = valid ? acc * 0.125f : -1e30f;
        }
        float lm = s[0];
#pragma unroll
        for (int cc = 1; cc < 8; ++cc) lm = fmaxf(lm, s[cc]);
        red[cg][r] = lm;
        __syncthreads();
        if (tid < QT) {
            float m = m_s[tid];
            float mc = red[0][tid];
#pragma unroll
            for (int g2 = 1; g2 < 8; ++g2) mc = fmaxf(mc, red[g2][tid]);
            const float mn = fmaxf(m, mc);
            alpha_s[tid] = __expf(m - mn);
            m_s[tid] = mn;
        }
        __syncthreads();
        const float mn = m_s[r];
        float ls = 0.0f;
#pragma unroll
        for (int cc = 0; cc < 8; ++cc) {
            const float p = __expf(s[cc] - mn);
            Ps[r][d0 + cc] = p;
            ls += p;
        }
        red[cg][r] = ls;
        __syncthreads();
        if (tid < QT) {
            float sum = red[0][tid];
#pragma unroll
            for (int g2 = 1; g2 < 8; ++g2) sum += red[g2][tid];
            l_s[tid] = l_s[tid] * alpha_s[tid] + sum;
        }
#pragma unroll
        for (int r4 = 0; r4 < 4; ++r4) {
            const int row = kr0 + r4 * 16;
            const int j = cs + row;
            float4 v = make_float4(0.f, 0.f, 0.f, 0.f);
            if (j < SEQ)
                v = *(const float4*)&Vm[(size_t)(b * SEQ + j) * ldv + h * HDIM + kc];
            *(float4*)&KVs[row][kc] = v;
        }
        {
            const float al = alpha_s[r];
#pragma unroll
            for (int dd = 0; dd < 8; ++dd) o[dd] *= al;
        }
        __syncthreads();
        for (int j = 0; j < KT; ++j) {
            const float p = Ps[r][j];
            float4 v0 = *(const float4*)&KVs[j][d0];
            float4 v1 = *(const float4*)&KVs[j][d0 + 4];
            o[0] = fmaf(p, v0.x, o[0]); o[1] = fmaf(p, v0.y, o[1]);
            o[2] = fmaf(p, v0.z, o[2]); o[3] = fmaf(p, v0.w, o[3]);
            o[4] = fmaf(p, v1.x, o[4]); o[5] = fmaf(p, v1.y, o[5]);
            o[6] = fmaf(p, v1.z, o[6]); o[7] = fmaf(p, v1.w, o[7]);
        }
        __syncthreads();
    }
    const float inv = 1.0f / l_s[r];
    float4 o0, o1;
    o0.x = o[0] * inv; o0.y = o[1] * inv; o0.z = o[2] * inv; o0.w = o[3] * inv;
    o1.x = o[4] * inv; o1.y = o[5] * inv; o1.z = o[6] * inv; o1.w = o[7] * inv;
    float* dst = Om + (size_t)(b * SEQ + q0 + r) * ldo + h * HDIM + d0;
    *(float4*)dst       = o0;
    *(float4*)(dst + 4) = o1;
}

// ---------------------------------------------------------------------------
extern "C" void kernel_launch(void* const* d_in, const int* in_sizes, int n_in,
                              void* d_out, int out_size, void* d_ws, size_t ws_size,
                              hipStream_t stream)
{
    const float* x  = (const float*)d_in[0];
    const float* Wq = (const float*)d_in[1];
    const float* bq = (const float*)d_in[2];
    const float* Wk = (const float*)d_in[3];
    const float* bk = (const float*)d_in[4];
    const float* Wv = (const float*)d_in[5];
    const float* bv = (const float*)d_in[6];
    const float* Wo = (const float*)d_in[7];
    const float* bo = (const float*)d_in[8];
    float* out = (float*)d_out;

    const int M = BATCH * SEQ;                 // 4096
    const size_t MK = (size_t)M * EMB;         // 4M elements

    const size_t need = ((size_t)40 << 20) + 16384;
    dim3 blk(256);

    if (ws_size >= need) {
        // ws layout (fp16):
        //  [0,8M)    Wcat^T  [4096][1024]  (Wq/8 | Wk | Wv | Wo)
        //  [8M,16M)  xh -> attn-out (reused)
        //  [16M,32M) QKb [4096][2048]  (Q/8 | K)
        //  [32M,40M) Vt  [2048][2048]  (V^T per b: rows h*64+d)
        //  [40M,+12K) bias_cat fp32
        unsigned short* Wh  = (unsigned short*)d_ws;
        unsigned short* xh  = Wh + (size_t)4096 * EMB;
        unsigned short* QKb = xh + MK;
        unsigned short* Vt  = QKb + (size_t)4096 * 2048;
        unsigned short* Oa  = xh;    // reuse after QKV GEMM consumed x
        float* bias_cat = (float*)((char*)d_ws + ((size_t)40 << 20));

        hipLaunchKernelGGL(cast16_kernel, dim3((int)(MK / (256 * 8))), blk, 0, stream,
                           x, xh, (int)MK);
        hipLaunchKernelGGL(wsplit16_t_kernel, dim3(32, 32, 4), blk, 0, stream,
                           Wq, Wk, Wv, Wo, Wh);
        hipLaunchKernelGGL(bias_cat_kernel, dim3(12), blk, 0, stream, bq, bk, bv, bias_cat);

        // fused QKV GEMM: Q,K -> QKb fp16; V -> Vt fp16 transposed
        hipLaunchKernelGGL(gemm_f16_qkv_kernel, dim3(24, 32), blk, 0, stream,
                           xh, Wh, bias_cat, (_Float16*)QKb, (_Float16*)Vt, EMB);

        // fp16 MFMA flash attention
        hipLaunchKernelGGL(attn_f16_kernel, dim3(1024), blk, 0, stream, QKb, Vt, Oa);

        // final GEMM: attn @ Wo + bo -> fp32 out (64x128 tiles, 512 blocks)
        hipLaunchKernelGGL(gemm_f16_m64_kernel, dim3(8, 64), blk, 0, stream,
                           Oa, Wh + (size_t)3072 * EMB, bo, out, EMB, EMB);
    } else {
        float* Qb = (float*)d_ws;
        float* Kb = Qb + MK;
        float* Vb = out;
        dim3 ggrid(EMB / BN, M / BM);
        hipLaunchKernelGGL(gemm_bias_kernel, ggrid, blk, 0, stream, x, Wq, bq, Qb, M, EMB, EMB);
        hipLaunchKernelGGL(gemm_bias_kernel, ggrid, blk, 0, stream, x, Wk, bk, Kb, M, EMB, EMB);
        hipLaunchKernelGGL(gemm_bias_kernel, ggrid, blk, 0, stream, x, Wv, bv, Vb, M, EMB, EMB);
        hipLaunchKernelGGL(attn_kernel, dim3(SEQ / QT, BATCH * NHEADS), blk, 0, stream,
                           Qb, EMB, Kb, EMB, Vb, EMB, Qb, EMB);
        hipLaunchKernelGGL(gemm_bias_kernel, ggrid, blk, 0, stream, Qb, Wo, bo, out, M, EMB, EMB);
    }
}

// Round 6
// 207.916 us; speedup vs baseline: 3.5466x; 1.0014x over previous
//
#include <hip/hip_runtime.h>
#include <math.h>
#include <stdint.h>

#define BATCH 2
#define SEQ   2048
#define EMB   1024
#define NHEADS 16
#define HDIM  64
#define WHALF 256      // WINDOW_SIZE/2

typedef __attribute__((ext_vector_type(8))) short short8;
typedef __attribute__((ext_vector_type(8))) _Float16 half8;
typedef __attribute__((ext_vector_type(4))) _Float16 half4;
typedef __attribute__((ext_vector_type(4))) float f32x4;

// ---------------------------------------------------------------------------
// cast fp32 -> fp16 (8 per thread)
// ---------------------------------------------------------------------------
__global__ __launch_bounds__(256)
void cast16_kernel(const float* __restrict__ in, unsigned short* __restrict__ o16, int n)
{
    const int i = (blockIdx.x * 256 + threadIdx.x) * 8;
    if (i >= n) return;
    float4 v0 = *(const float4*)&in[i];
    float4 v1 = *(const float4*)&in[i + 4];
    half8 h;
    h[0] = (_Float16)v0.x; h[1] = (_Float16)v0.y;
    h[2] = (_Float16)v0.z; h[3] = (_Float16)v0.w;
    h[4] = (_Float16)v1.x; h[5] = (_Float16)v1.y;
    h[6] = (_Float16)v1.z; h[7] = (_Float16)v1.w;
    *(half8*)&o16[i] = h;
}

// ---------------------------------------------------------------------------
// transpose + cast the four 1024x1024 weights into one cat [4096][1024] fp16
// buffer (Wq^T/8 | Wk^T | Wv^T | Wo^T).
// ---------------------------------------------------------------------------
__global__ __launch_bounds__(256)
void wsplit16_t_kernel(const float* __restrict__ W0, const float* __restrict__ W1,
                       const float* __restrict__ W2, const float* __restrict__ W3,
                       unsigned short* __restrict__ o16)
{
    __shared__ float t[32][33];
    const float* W = (blockIdx.z == 0) ? W0 : (blockIdx.z == 1) ? W1
                   : (blockIdx.z == 2) ? W2 : W3;
    const float scale = (blockIdx.z == 0) ? 0.125f : 1.0f;
    const int n0 = blockIdx.x * 32;
    const int k0 = blockIdx.y * 32;
    const int tx = threadIdx.x & 31, ty = threadIdx.x >> 5;
#pragma unroll
    for (int i = 0; i < 4; ++i)
        t[ty + i * 8][tx] = W[(size_t)(k0 + ty + i * 8) * EMB + n0 + tx];
    __syncthreads();
#pragma unroll
    for (int i = 0; i < 4; ++i) {
        float v = t[tx][ty + i * 8] * scale;
        size_t o = (size_t)(blockIdx.z * EMB + n0 + ty + i * 8) * EMB + k0 + tx;
        *(_Float16*)&o16[o] = (_Float16)v;
    }
}

__global__ __launch_bounds__(256)
void bias_cat_kernel(const float* __restrict__ bq, const float* __restrict__ bk,
                     const float* __restrict__ bv, float* __restrict__ out)
{
    const int i = blockIdx.x * 256 + threadIdx.x;
    if (i < 1024)      out[i] = bq[i] * 0.125f;
    else if (i < 2048) out[i] = bk[i - 1024];
    else if (i < 3072) out[i] = bv[i - 2048];
}

#define GLDS(gp, lp) __builtin_amdgcn_global_load_lds(                       \
    (const __attribute__((address_space(1))) void*)(gp),                     \
    (__attribute__((address_space(3))) void*)(lp), 16, 0, 0)

// ---------------------------------------------------------------------------
// QKV fp16 MFMA GEMM: C = A @ B^T + bias.  A:[4096][1024] fp16, B:[3072][1024].
// 128x128 tile, BK=32. Epilogue staged through LDS for coalesced writes;
// the epilogue buffer ALIASES the K-loop staging LDS (live ranges disjoint)
// so LDS/block = 34.8 KB -> 4 blocks/CU.
//   cols < 2048 -> QK fp16 [4096][2048] row-major
//   cols >= 2048 -> Vt fp16 transposed: Vt[b*1024 + (col-2048)][s]
// ---------------------------------------------------------------------------
#define TRS 136   // tr row stride in halves (272 B)

__global__ __launch_bounds__(256)
void gemm_f16_qkv_kernel(const unsigned short* __restrict__ A,
                         const unsigned short* __restrict__ B,
                         const float* __restrict__ bias,
                         _Float16* __restrict__ QK,
                         _Float16* __restrict__ Vt, int K)
{
    __shared__ __align__(16) unsigned short smem[128 * TRS];  // 34816 B
    unsigned short* sA = smem;            // [128*32] during K-loop
    unsigned short* sB = smem + 4096;     // [128*32] during K-loop
    _Float16* tr = (_Float16*)smem;       // [128][TRS] during epilogue

    const int tid = threadIdx.x;
    const int l = tid & 63;
    const int w = tid >> 6;
    const int wm = w >> 1, wn = w & 1;
    const int row0 = blockIdx.y * 128;
    const int col0 = blockIdx.x * 128;

    f32x4 acc[4][4] = {};

    const int sr = tid >> 2;
    const int sk = (tid & 3) * 8;
    const unsigned short* pA = A + (size_t)(row0 + sr) * K + sk;
    const unsigned short* pB = B + (size_t)(col0 + sr) * K + sk;
    const size_t rstep = (size_t)64 * K;

    const int kq = (l >> 4) * 8;
    const int lr = l & 15;
    const int lq = l >> 4;

    for (int k0 = 0; k0 < K; k0 += 32) {
        GLDS(pA + k0,         &sA[tid * 8]);
        GLDS(pA + rstep + k0, &sA[2048 + tid * 8]);
        GLDS(pB + k0,         &sB[tid * 8]);
        GLDS(pB + rstep + k0, &sB[2048 + tid * 8]);
        __syncthreads();

        half8 af[4], bf[4];
#pragma unroll
        for (int f = 0; f < 4; ++f) {
            af[f] = *(const half8*)&sA[(wm * 64 + f * 16 + lr) * 32 + kq];
            bf[f] = *(const half8*)&sB[(wn * 64 + f * 16 + lr) * 32 + kq];
        }
#pragma unroll
        for (int mf = 0; mf < 4; ++mf)
#pragma unroll
            for (int nf = 0; nf < 4; ++nf)
                acc[mf][nf] = __builtin_amdgcn_mfma_f32_16x16x32_f16(af[mf], bf[nf], acc[mf][nf], 0, 0, 0);
        __syncthreads();
    }

    // ---- epilogue via aliased LDS (coalesced global writes) ----
    if (col0 < 2048) {
        // QK: tr[r_local][c]
#pragma unroll
        for (int nf = 0; nf < 4; ++nf) {
            const int c = wn * 64 + nf * 16 + lr;
            const float bv = bias[col0 + c];
#pragma unroll
            for (int mf = 0; mf < 4; ++mf) {
                const int rl = wm * 64 + mf * 16 + lq * 4;
#pragma unroll
                for (int i = 0; i < 4; ++i)
                    tr[(rl + i) * TRS + c] = (_Float16)(acc[mf][nf][i] + bv);
            }
        }
        __syncthreads();
        const int r = tid >> 1, seg = (tid & 1) * 64;
        _Float16* dst = QK + (size_t)(row0 + r) * 2048 + col0 + seg;
#pragma unroll
        for (int t = 0; t < 8; ++t)
            *(half8*)&dst[t * 8] = *(const half8*)&tr[r * TRS + seg + t * 8];
    } else {
        // V: tr[c][r_local]  (transpose in LDS)
#pragma unroll
        for (int nf = 0; nf < 4; ++nf) {
            const int c = wn * 64 + nf * 16 + lr;
            const float bv = bias[col0 + c];
#pragma unroll
            for (int mf = 0; mf < 4; ++mf) {
                const int rl = wm * 64 + mf * 16 + lq * 4;
#pragma unroll
                for (int i = 0; i < 4; ++i)
                    tr[c * TRS + rl + i] = (_Float16)(acc[mf][nf][i] + bv);
            }
        }
        __syncthreads();
        const int c = tid >> 1, seg = (tid & 1) * 64;
        const int vb = row0 >> 11;             // batch index
        const int s0 = (row0 & 2047) + seg;
        _Float16* dst = Vt + ((size_t)(vb * 1024 + (col0 - 2048) + c)) * 2048 + s0;
#pragma unroll
        for (int t = 0; t < 8; ++t)
            *(half8*)&dst[t * 8] = *(const half8*)&tr[c * TRS + seg + t * 8];
    }
}

// ---------------------------------------------------------------------------
// final fp16 MFMA GEMM, 64x128 tile (2 blocks/CU): C fp32 = A @ B^T + bias
// ---------------------------------------------------------------------------
__global__ __launch_bounds__(256)
void gemm_f16_m64_kernel(const unsigned short* __restrict__ A,
                         const unsigned short* __restrict__ B,
                         const float* __restrict__ bias,
                         float* __restrict__ C, int ldc, int K)
{
    __shared__ unsigned short sA[64 * 32], sB[128 * 32];

    const int tid = threadIdx.x;
    const int l = tid & 63;
    const int w = tid >> 6;
    const int wm = w >> 1, wn = w & 1;
    const int row0 = blockIdx.y * 64;
    const int col0 = blockIdx.x * 128;

    f32x4 acc[2][4] = {};

    const int sr = tid >> 2;
    const int sk = (tid & 3) * 8;
    const unsigned short* pA = A + (size_t)(row0 + sr) * K + sk;
    const unsigned short* pB = B + (size_t)(col0 + sr) * K + sk;
    const size_t rstep = (size_t)64 * K;

    const int kq = (l >> 4) * 8;
    const int lr = l & 15;
    const int lq = l >> 4;

    for (int k0 = 0; k0 < K; k0 += 32) {
        GLDS(pA + k0,         &sA[tid * 8]);
        GLDS(pB + k0,         &sB[tid * 8]);
        GLDS(pB + rstep + k0, &sB[2048 + tid * 8]);
        __syncthreads();

        half8 af[2], bf[4];
#pragma unroll
        for (int f = 0; f < 2; ++f)
            af[f] = *(const half8*)&sA[(wm * 32 + f * 16 + lr) * 32 + kq];
#pragma unroll
        for (int f = 0; f < 4; ++f)
            bf[f] = *(const half8*)&sB[(wn * 64 + f * 16 + lr) * 32 + kq];
#pragma unroll
        for (int mf = 0; mf < 2; ++mf)
#pragma unroll
            for (int nf = 0; nf < 4; ++nf)
                acc[mf][nf] = __builtin_amdgcn_mfma_f32_16x16x32_f16(af[mf], bf[nf], acc[mf][nf], 0, 0, 0);
        __syncthreads();
    }

#pragma unroll
    for (int nf = 0; nf < 4; ++nf) {
        const int c = wn * 64 + nf * 16 + lr;
        const float bv = bias[col0 + c];
#pragma unroll
        for (int mf = 0; mf < 2; ++mf) {
            const int r = row0 + wm * 32 + mf * 16 + lq * 4;
#pragma unroll
            for (int i = 0; i < 4; ++i)
                C[(size_t)(r + i) * ldc + col0 + c] = acc[mf][nf][i] + bv;
        }
    }
}

// ---------------------------------------------------------------------------
// fp16 MFMA sliding-window flash attention, S^T softmax orientation.
// 128-query tile, 512 threads = 8 waves (wave w owns q rows q0+w*16..+15).
// QKb: [B*S][2048] fp16 (Q/8 | K).  Vt: [(b*1024+h*64+d)][2048] fp16.
// 64-key chunks over [q0-256, q0+127+256] (10 chunks); lower mask c<=1,
// upper mask c>=8. Softmax per lane (one q row), 2-shuffle reduce.
// Output: fp16 [B*S][1024]. Grid 512, gid&7 = XCD slot.
// ---------------------------------------------------------------------------
#define AP 66   // padded LDS row stride (halves)

__global__ __launch_bounds__(512)
void attn_f16_kernel(const unsigned short* __restrict__ QKb,
                     const unsigned short* __restrict__ Vt,
                     unsigned short* __restrict__ Oa)
{
    __shared__ unsigned short Qs[128 * AP], Ks[64 * AP], Vs[64 * AP], Ps[128 * AP];

    const int tid = threadIdx.x;
    const int gid = blockIdx.x;
    const int X = gid & 7, rest = gid >> 3;
    const int hg = rest & 3, tile = rest >> 2;     // tile 0..15
    const int bh = X * 4 + hg;
    const int b = bh >> 4, h = bh & 15;
    const int q0 = tile * 128;

    const int l = tid & 63, w = tid >> 6;          // w 0..7
    const int lr = l & 15, g = l >> 4;

    const size_t rowbase = (size_t)b * SEQ;

    // stage Q tile (128 rows x 64 halves)
    {
        const int r = tid >> 2, sg = (tid & 3) * 16;
        const unsigned short* src = QKb + (rowbase + q0 + r) * 2048 + h * HDIM + sg;
        *(short8*)&Qs[r * AP + sg]     = *(const short8*)src;
        *(short8*)&Qs[r * AP + sg + 8] = *(const short8*)(src + 8);
    }
    __syncthreads();

    half8 qa0 = *(const half8*)&Qs[(w * 16 + lr) * AP + g * 8];
    half8 qa1 = *(const half8*)&Qs[(w * 16 + lr) * AP + 32 + g * 8];

    f32x4 o[4] = {};
    float m_ = -1e30f, l_ = 0.0f;            // state for q = q0 + w*16 + lr
    const int q = q0 + w * 16 + lr;

    const int c_begin = (q0 >= WHALF) ? 0 : (WHALF - q0) >> 6;
    int c_end = (SEQ + 255 - q0) >> 6; if (c_end > 9) c_end = 9;

    for (int c = c_begin; c <= c_end; ++c) {
        const int cs = q0 - WHALF + c * 64;

        // stage K chunk + V^T chunk (64 rows x 64 halves each; 1 short8/thr)
        {
            const int r = tid >> 3, sg = (tid & 7) * 8;
            const unsigned short* ks = QKb + (rowbase + cs + r) * 2048 + 1024 + h * HDIM + sg;
            *(short8*)&Ks[r * AP + sg] = *(const short8*)ks;
            const unsigned short* vs = Vt + ((size_t)(b * 1024 + h * HDIM + r)) * 2048 + cs + sg;
            *(short8*)&Vs[r * AP + sg] = *(const short8*)vs;
        }
        __syncthreads();

        // ---- S^T = K Q^T : row=key, col=q (lr) ----
        f32x4 sc[4] = {};
#pragma unroll
        for (int kf = 0; kf < 4; ++kf) {
            half8 a0 = *(const half8*)&Ks[(kf * 16 + lr) * AP + g * 8];
            half8 a1 = *(const half8*)&Ks[(kf * 16 + lr) * AP + 32 + g * 8];
            sc[kf] = __builtin_amdgcn_mfma_f32_16x16x32_f16(a0, qa0, sc[kf], 0, 0, 0);
            sc[kf] = __builtin_amdgcn_mfma_f32_16x16x32_f16(a1, qa1, sc[kf], 0, 0, 0);
        }

        // ---- window mask (edge chunks only) ----
        if (c <= 1) {
#pragma unroll
            for (int kf = 0; kf < 4; ++kf)
#pragma unroll
                for (int i = 0; i < 4; ++i) {
                    const int key = cs + kf * 16 + g * 4 + i;
                    if (key < q - WHALF) sc[kf][i] = -1e30f;
                }
        } else if (c >= 8) {
#pragma unroll
            for (int kf = 0; kf < 4; ++kf)
#pragma unroll
                for (int i = 0; i < 4; ++i) {
                    const int key = cs + kf * 16 + g * 4 + i;
                    if (key > q + WHALF) sc[kf][i] = -1e30f;
                }
        }

        // ---- online softmax: all 16 values belong to q=lr -> 2-step reduce ----
        float cm = sc[0][0];
#pragma unroll
        for (int kf = 0; kf < 4; ++kf)
#pragma unroll
            for (int i = 0; i < 4; ++i) cm = fmaxf(cm, sc[kf][i]);
        cm = fmaxf(cm, __shfl_xor(cm, 16));
        cm = fmaxf(cm, __shfl_xor(cm, 32));

        const float mn = fmaxf(fmaxf(m_, cm), -1e4f);
        const float alpha = __expf(m_ - mn);
        m_ = mn;

        float rs = 0.0f;
#pragma unroll
        for (int kf = 0; kf < 4; ++kf) {
            half4 pk;
#pragma unroll
            for (int i = 0; i < 4; ++i) {
                const float p = __expf(sc[kf][i] - mn);
                rs += p;
                pk[i] = (_Float16)p;
            }
            *(half4*)&Ps[(w * 16 + lr) * AP + kf * 16 + g * 4] = pk;
        }
        rs += __shfl_xor(rs, 16);
        rs += __shfl_xor(rs, 32);
        l_ = l_ * alpha + rs;

        // broadcast alpha to this lane's accumulator rows (q = g*4+i)
        float al[4];
#pragma unroll
        for (int i = 0; i < 4; ++i)
            al[i] = __shfl(alpha, (l & 48) | (g * 4 + i));
#pragma unroll
        for (int df = 0; df < 4; ++df)
#pragma unroll
            for (int i = 0; i < 4; ++i) o[df][i] *= al[i];

        // ---- P @ V ----  (Ps rows are wave-private; Vs synced above)
        half8 pa0 = *(const half8*)&Ps[(w * 16 + lr) * AP + g * 8];
        half8 pa1 = *(const half8*)&Ps[(w * 16 + lr) * AP + 32 + g * 8];
#pragma unroll
        for (int df = 0; df < 4; ++df) {
            half8 vb0 = *(const half8*)&Vs[(df * 16 + lr) * AP + g * 8];
            half8 vb1 = *(const half8*)&Vs[(df * 16 + lr) * AP + 32 + g * 8];
            o[df] = __builtin_amdgcn_mfma_f32_16x16x32_f16(pa0, vb0, o[df], 0, 0, 0);
            o[df] = __builtin_amdgcn_mfma_f32_16x16x32_f16(pa1, vb1, o[df], 0, 0, 0);
        }
        __syncthreads();   // Ks/Vs reads done before next chunk's staging
    }

    // ---- epilogue: per-row 1/l broadcast, store fp16 ----
    float invl[4];
#pragma unroll
    for (int i = 0; i < 4; ++i)
        invl[i] = 1.0f / __shfl(l_, (l & 48) | (g * 4 + i));
#pragma unroll
    for (int df = 0; df < 4; ++df)
#pragma unroll
        for (int i = 0; i < 4; ++i) {
            const float v = o[df][i] * invl[i];
            const size_t off = (rowbase + q0 + w * 16 + g * 4 + i) * 1024
                             + h * HDIM + df * 16 + lr;
            *(_Float16*)&Oa[off] = (_Float16)v;
        }
}

// ---------------------------------------------------------------------------
// fp32 fallback GEMM + attention (only if ws too small)
// ---------------------------------------------------------------------------
#define BM 64
#define BN 64
#define BK 16

__global__ __launch_bounds__(256)
void gemm_bias_kernel(const float* __restrict__ A, const float* __restrict__ W,
                      const float* __restrict__ bias, float* __restrict__ C,
                      int M, int N, int K)
{
    __shared__ float As[BK][BM + 4];
    __shared__ float Bs[BK][BN + 4];
    const int tid = threadIdx.x;
    const int tx = tid & 15, ty = tid >> 4;
    const int row0 = blockIdx.y * BM;
    const int col0 = blockIdx.x * BN;
    float acc[4][4] = {};
    const int ar = tid >> 2;
    const int ak = (tid & 3) * 4;
    const int br = tid >> 4;
    const int bc = (tid & 15) * 4;
    for (int k0 = 0; k0 < K; k0 += BK) {
        float4 a = *(const float4*)&A[(size_t)(row0 + ar) * K + k0 + ak];
        float4 b = *(const float4*)&W[(size_t)(k0 + br) * N + col0 + bc];
        As[ak + 0][ar] = a.x; As[ak + 1][ar] = a.y;
        As[ak + 2][ar] = a.z; As[ak + 3][ar] = a.w;
        *(float4*)&Bs[br][bc] = b;
        __syncthreads();
#pragma unroll
        for (int kk = 0; kk < BK; ++kk) {
            float4 av = *(const float4*)&As[kk][ty * 4];
            float4 bv = *(const float4*)&Bs[kk][tx * 4];
            float aa[4] = {av.x, av.y, av.z, av.w};
            float bb[4] = {bv.x, bv.y, bv.z, bv.w};
#pragma unroll
            for (int i = 0; i < 4; ++i)
#pragma unroll
                for (int j = 0; j < 4; ++j)
                    acc[i][j] = fmaf(aa[i], bb[j], acc[i][j]);
        }
        __syncthreads();
    }
    const float4 bvec = *(const float4*)&bias[col0 + tx * 4];
    const float bb[4] = {bvec.x, bvec.y, bvec.z, bvec.w};
#pragma unroll
    for (int i = 0; i < 4; ++i) {
        float4 oo;
        oo.x = acc[i][0] + bb[0]; oo.y = acc[i][1] + bb[1];
        oo.z = acc[i][2] + bb[2]; oo.w = acc[i][3] + bb[3];
        *(float4*)&C[(size_t)(row0 + ty * 4 + i) * N + col0 + tx * 4] = oo;
    }
}

#define QT 32
#define KT 64

__global__ __launch_bounds__(256)
void attn_kernel(const float* __restrict__ Qm, int ldq,
                 const float* __restrict__ Km, int ldk,
                 const float* __restrict__ Vm, int ldv,
                 float* __restrict__ Om, int ldo)
{
    __shared__ float Qs[QT][HDIM + 4];
    __shared__ float KVs[KT][HDIM + 4];
    __shared__ float Ps[QT][KT + 1];
    __shared__ float red[8][QT];
    __shared__ float m_s[QT], l_s[QT], alpha_s[QT];
    const int tid = threadIdx.x;
    const int b  = blockIdx.y / NHEADS;
    const int h  = blockIdx.y % NHEADS;
    const int q0 = blockIdx.x * QT;
    const int r  = tid & 31;
    const int cg = tid >> 5;
    const int d0 = cg * 8;
    {
        const int qr = tid >> 3;
        const int qd = (tid & 7) * 8;
        const float* src = Qm + (size_t)(b * SEQ + q0 + qr) * ldq + h * HDIM + qd;
        *(float4*)&Qs[qr][qd]     = *(const float4*)(src);
        *(float4*)&Qs[qr][qd + 4] = *(const float4*)(src + 4);
    }
    if (tid < QT) { m_s[tid] = -1e30f; l_s[tid] = 0.0f; }
    __syncthreads();
    float qreg[HDIM];
#pragma unroll
    for (int d4 = 0; d4 < HDIM; d4 += 4) {
        float4 t = *(const float4*)&Qs[r][d4];
        qreg[d4] = t.x; qreg[d4 + 1] = t.y; qreg[d4 + 2] = t.z; qreg[d4 + 3] = t.w;
    }
    float o[8] = {};
    const int iq = q0 + r;
    int lo = q0 - WHALF; if (lo < 0) lo = 0;
    const int cs0 = lo & ~(KT - 1);
    int hi = q0 + QT + WHALF; if (hi > SEQ) hi = SEQ;
    const int nch = (hi - cs0 + KT - 1) / KT;
    const int kr0 = tid >> 4;
    const int kc  = (tid & 15) * 4;
    for (int ch = 0; ch < nch; ++ch) {
        const int cs = cs0 + ch * KT;
#pragma unroll
        for (int r4 = 0; r4 < 4; ++r4) {
            const int row = kr0 + r4 * 16;
            const int j = cs + row;
            float4 v = make_float4(0.f, 0.f, 0.f, 0.f);
            if (j < SEQ)
                v = *(const float4*)&Km[(size_t)(b * SEQ + j) * ldk + h * HDIM + kc];
            *(float4*)&KVs[row][kc] = v;
        }
        __syncthreads();
        float s[8];
#pragma unroll
        for (int cc = 0; cc < 8; ++cc) {
            const int cidx = d0 + cc;
            float acc = 0.0f;
#pragma unroll
            for (int d4 = 0; d4 < HDIM; d4 += 4) {
                float4 kv = *(const float4*)&KVs[cidx][d4];
                acc = fmaf(qreg[d4],     kv.x, acc);
                acc = fmaf(qreg[d4 + 1], kv.y, acc);
                acc = fmaf(qreg[d4 + 2], kv.z, acc);
                acc = fmaf(qreg[d4 + 3], kv.w, acc);
            }
            const int j = cs + cidx;
            const bool valid = (j < SEQ) && (j >= iq - WHALF) && (j <= iq + WHALF);
            s[cc] = valid ? acc * 0.125f : -1e30f;
        }
        float lm = s[0];
#pragma unroll
        for (int cc = 1; cc < 8; ++cc) lm = fmaxf(lm, s[cc]);
        red[cg][r] = lm;
        __syncthreads();
        if (tid < QT) {
            float m = m_s[tid];
            float mc = red[0][tid];
#pragma unroll
            for (int g2 = 1; g2 < 8; ++g2) mc = fmaxf(mc, red[g2][tid]);
            const float mn = fmaxf(m, mc);
            alpha_s[tid] = __expf(m - mn);
            m_s[tid] = mn;
        }
        __syncthreads();
        const float mn = m_s[r];
        float ls = 0.0f;
#pragma unroll
        for (int cc = 0; cc < 8; ++cc) {
            const float p = __expf(s[cc] - mn);
            Ps[r][d0 + cc] = p;
            ls += p;
        }
        red[cg][r] = ls;
        __syncthreads();
        if (tid < QT) {
            float sum = red[0][tid];
#pragma unroll
            for (int g2 = 1; g2 < 8; ++g2) sum += red[g2][tid];
            l_s[tid] = l_s[tid] * alpha_s[tid] + sum;
        }
#pragma unroll
        for (int r4 = 0; r4 < 4; ++r4) {
            const int row = kr0 + r4 * 16;
            const int j = cs + row;
            float4 v = make_float4(0.f, 0.f, 0.f, 0.f);
            if (j < SEQ)
                v = *(const float4*)&Vm[(size_t)(b * SEQ + j) * ldv + h * HDIM + kc];
            *(float4*)&KVs[row][kc] = v;
        }
        {
            const float al = alpha_s[r];
#pragma unroll
            for (int dd = 0; dd < 8; ++dd) o[dd] *= al;
        }
        __syncthreads();
        for (int j = 0; j < KT; ++j) {
            const float p = Ps[r][j];
            float4 v0 = *(const float4*)&KVs[j][d0];
            float4 v1 = *(const float4*)&KVs[j][d0 + 4];
            o[0] = fmaf(p, v0.x, o[0]); o[1] = fmaf(p, v0.y, o[1]);
            o[2] = fmaf(p, v0.z, o[2]); o[3] = fmaf(p, v0.w, o[3]);
            o[4] = fmaf(p, v1.x, o[4]); o[5] = fmaf(p, v1.y, o[5]);
            o[6] = fmaf(p, v1.z, o[6]); o[7] = fmaf(p, v1.w, o[7]);
        }
        __syncthreads();
    }
    const float inv = 1.0f / l_s[r];
    float4 o0, o1;
    o0.x = o[0] * inv; o0.y = o[1] * inv; o0.z = o[2] * inv; o0.w = o[3] * inv;
    o1.x = o[4] * inv; o1.y = o[5] * inv; o1.z = o[6] * inv; o1.w = o[7] * inv;
    float* dst = Om + (size_t)(b * SEQ + q0 + r) * ldo + h * HDIM + d0;
    *(float4*)dst       = o0;
    *(float4*)(dst + 4) = o1;
}

// ---------------------------------------------------------------------------
extern "C" void kernel_launch(void* const* d_in, const int* in_sizes, int n_in,
                              void* d_out, int out_size, void* d_ws, size_t ws_size,
                              hipStream_t stream)
{
    const float* x  = (const float*)d_in[0];
    const float* Wq = (const float*)d_in[1];
    const float* bq = (const float*)d_in[2];
    const float* Wk = (const float*)d_in[3];
    const float* bk = (const float*)d_in[4];
    const float* Wv = (const float*)d_in[5];
    const float* bv = (const float*)d_in[6];
    const float* Wo = (const float*)d_in[7];
    const float* bo = (const float*)d_in[8];
    float* out = (float*)d_out;

    const int M = BATCH * SEQ;                 // 4096
    const size_t MK = (size_t)M * EMB;         // 4M elements

    const size_t need = ((size_t)40 << 20) + 16384;
    dim3 blk(256);

    if (ws_size >= need) {
        // ws layout (fp16):
        //  [0,8M)    Wcat^T  [4096][1024]  (Wq/8 | Wk | Wv | Wo)
        //  [8M,16M)  xh -> attn-out (reused)
        //  [16M,32M) QKb [4096][2048]  (Q/8 | K)
        //  [32M,40M) Vt  [2048][2048]  (V^T per b: rows h*64+d)
        //  [40M,+12K) bias_cat fp32
        unsigned short* Wh  = (unsigned short*)d_ws;
        unsigned short* xh  = Wh + (size_t)4096 * EMB;
        unsigned short* QKb = xh + MK;
        unsigned short* Vt  = QKb + (size_t)4096 * 2048;
        unsigned short* Oa  = xh;    // reuse after QKV GEMM consumed x
        float* bias_cat = (float*)((char*)d_ws + ((size_t)40 << 20));

        hipLaunchKernelGGL(cast16_kernel, dim3((int)(MK / (256 * 8))), blk, 0, stream,
                           x, xh, (int)MK);
        hipLaunchKernelGGL(wsplit16_t_kernel, dim3(32, 32, 4), blk, 0, stream,
                           Wq, Wk, Wv, Wo, Wh);
        hipLaunchKernelGGL(bias_cat_kernel, dim3(12), blk, 0, stream, bq, bk, bv, bias_cat);

        // fused QKV GEMM: Q,K -> QKb fp16; V -> Vt fp16 transposed
        hipLaunchKernelGGL(gemm_f16_qkv_kernel, dim3(24, 32), blk, 0, stream,
                           xh, Wh, bias_cat, (_Float16*)QKb, (_Float16*)Vt, EMB);

        // fp16 MFMA flash attention (128-q tiles, 512-thread blocks)
        hipLaunchKernelGGL(attn_f16_kernel, dim3(512), dim3(512), 0, stream, QKb, Vt, Oa);

        // final GEMM: attn @ Wo + bo -> fp32 out (64x128 tiles, 512 blocks)
        hipLaunchKernelGGL(gemm_f16_m64_kernel, dim3(8, 64), blk, 0, stream,
                           Oa, Wh + (size_t)3072 * EMB, bo, out, EMB, EMB);
    } else {
        float* Qb = (float*)d_ws;
        float* Kb = Qb + MK;
        float* Vb = out;
        dim3 ggrid(EMB / BN, M / BM);
        hipLaunchKernelGGL(gemm_bias_kernel, ggrid, blk, 0, stream, x, Wq, bq, Qb, M, EMB, EMB);
        hipLaunchKernelGGL(gemm_bias_kernel, ggrid, blk, 0, stream, x, Wk, bk, Kb, M, EMB, EMB);
        hipLaunchKernelGGL(gemm_bias_kernel, ggrid, blk, 0, stream, x, Wv, bv, Vb, M, EMB, EMB);
        hipLaunchKernelGGL(attn_kernel, dim3(SEQ / QT, BATCH * NHEADS), blk, 0, stream,
                           Qb, EMB, Kb, EMB, Vb, EMB, Qb, EMB);
        hipLaunchKernelGGL(gemm_bias_kernel, ggrid, blk, 0, stream, Qb, Wo, bo, out, M, EMB, EMB);
    }
}